// Round 10
// baseline (747.394 us; speedup 1.0000x reference)
//
#include <hip/hip_runtime.h>
#include <hip/hip_fp16.h>

#define N_NODES 50000
#define N_EDGES 600000
#define F_IN    500
#define H_DIM   64
#define C_OUT   40
#define STEPS   4
#define NB_SCAN ((N_NODES + 255) / 256)   // 196
#define KTILES  16                        // 512 k padded, 32 per MFMA
#define DBINS   64                        // degree bins for counting sort

using half8 = __attribute__((ext_vector_type(8))) _Float16;
using f32x4 = __attribute__((ext_vector_type(4))) float;

// ---------------- B-fragment precompute: W (500x64 f32) -> MFMA frags ------
__global__ __launch_bounds__(256) void bfrag_kernel(
    const float* __restrict__ W, __half* __restrict__ bfrag)
{
    int t = blockIdx.x * 256 + threadIdx.x;
    if (t >= KTILES * 4 * 64) return;
    int lane = t & 63;
    int c    = (t >> 6) & 3;
    int kt   = t >> 8;
    int col  = c * 16 + (lane & 15);
    int kb   = kt * 32 + (lane >> 4) * 8;
    union { uint4 u; __half h[8]; } v;
    #pragma unroll
    for (int j = 0; j < 8; ++j) {
        int k = kb + j;
        v.h[j] = (k < F_IN) ? __float2half(W[(size_t)k * H_DIM + col]) : __half(0.f);
    }
    *reinterpret_cast<uint4*>(bfrag + (size_t)t * 8) = v.u;
}

// ---------------- Encoder: MFMA GEMM, K-split pairs + full x prefetch ------
__global__ __launch_bounds__(256) void encoder_kernel(
    const float* __restrict__ x, const __half* __restrict__ bfrag,
    const float* __restrict__ b, __half* __restrict__ x0H,
    float* __restrict__ zF, __half* __restrict__ zH)
{
    __shared__ f32x4 red[2][64][4];   // 8 KB

    int wave = threadIdx.x >> 6;
    int lane = threadIdx.x & 63;
    int pair = wave >> 1;
    int half = wave & 1;
    int rowl = lane & 15;
    int kg   = lane >> 4;              // 0..3
    int r0   = blockIdx.x * 32 + pair * 16;

    int gr = r0 + rowl; if (gr >= N_NODES) gr = N_NODES - 1;
    const float* xrow = x + (size_t)gr * F_IN;
    const uint4* bf = reinterpret_cast<const uint4*>(bfrag);

    int ktb = half * 8;

    float4 xv[16];
    #pragma unroll
    for (int ki = 0; ki < 8; ++ki) {
        int k0 = (ktb + ki) * 32 + kg * 8;
        xv[2 * ki]     = make_float4(0.f, 0.f, 0.f, 0.f);
        xv[2 * ki + 1] = make_float4(0.f, 0.f, 0.f, 0.f);
        if (k0 + 4 <= F_IN) xv[2 * ki]     = *reinterpret_cast<const float4*>(xrow + k0);
        if (k0 + 8 <= F_IN) xv[2 * ki + 1] = *reinterpret_cast<const float4*>(xrow + k0 + 4);
    }

    f32x4 acc[4];
    #pragma unroll
    for (int c = 0; c < 4; ++c) acc[c] = (f32x4){0.f, 0.f, 0.f, 0.f};

    #pragma unroll
    for (int ki = 0; ki < 8; ++ki) {
        int kt = ktb + ki;
        float4 xa = xv[2 * ki], xb = xv[2 * ki + 1];
        half8 a;
        a[0] = (_Float16)xa.x; a[1] = (_Float16)xa.y;
        a[2] = (_Float16)xa.z; a[3] = (_Float16)xa.w;
        a[4] = (_Float16)xb.x; a[5] = (_Float16)xb.y;
        a[6] = (_Float16)xb.z; a[7] = (_Float16)xb.w;
        #pragma unroll
        for (int c = 0; c < 4; ++c) {
            union { uint4 u; half8 h; } bv;
            bv.u = bf[(size_t)(kt * 4 + c) * 64 + lane];
            acc[c] = __builtin_amdgcn_mfma_f32_16x16x32_f16(a, bv.h, acc[c], 0, 0, 0);
        }
    }

    if (half == 1) {
        #pragma unroll
        for (int c = 0; c < 4; ++c) red[pair][lane][c] = acc[c];
    }
    __syncthreads();
    if (half == 0) {
        #pragma unroll
        for (int c = 0; c < 4; ++c) {
            f32x4 r = red[pair][lane][c];
            acc[c][0] += r[0]; acc[c][1] += r[1];
            acc[c][2] += r[2]; acc[c][3] += r[3];
        }
        #pragma unroll
        for (int c = 0; c < 4; ++c) {
            int col = c * 16 + rowl;
            float bias = b[col];
            #pragma unroll
            for (int r = 0; r < 4; ++r) {
                int grow = r0 + kg * 4 + r;
                if (grow < N_NODES) {
                    float v = acc[c][r] + bias;
                    size_t idx = (size_t)grow * H_DIM + col;
                    zF[idx]  = v;
                    __half hv = __float2half(v);
                    zH[idx]  = hv;
                    x0H[idx] = hv;
                }
            }
        }
    }
}

// ---------------- CSR build ----------------
__global__ void hist_kernel(const int* __restrict__ src, int* __restrict__ counts)
{
    int e = blockIdx.x * 256 + threadIdx.x;
    if (e < N_EDGES) atomicAdd(&counts[src[e]], 1);
}

__global__ __launch_bounds__(256) void scanA_kernel(
    const int* __restrict__ counts, int* __restrict__ blockSums)
{
    __shared__ int red[256];
    int i = blockIdx.x * 256 + threadIdx.x;
    red[threadIdx.x] = (i < N_NODES) ? counts[i] : 0;
    __syncthreads();
    #pragma unroll
    for (int s = 128; s > 0; s >>= 1) {
        if (threadIdx.x < s) red[threadIdx.x] += red[threadIdx.x + s];
        __syncthreads();
    }
    if (threadIdx.x == 0) blockSums[blockIdx.x] = red[0];
}

__global__ __launch_bounds__(256) void scanB_kernel(
    const int* __restrict__ blockSums, int* __restrict__ blockBases)
{
    __shared__ int s[256];
    int tid = threadIdx.x;
    int v = (tid < NB_SCAN) ? blockSums[tid] : 0;
    s[tid] = v;
    __syncthreads();
    #pragma unroll
    for (int d = 1; d < 256; d <<= 1) {
        int t = (tid >= d) ? s[tid - d] : 0;
        __syncthreads();
        s[tid] += t;
        __syncthreads();
    }
    if (tid < NB_SCAN) blockBases[tid] = s[tid] - v;
}

__global__ __launch_bounds__(256) void scanC_kernel(
    const int* __restrict__ counts, const int* __restrict__ blockBases,
    int* __restrict__ off, int* __restrict__ cursor)
{
    __shared__ int s[256];
    int tid = threadIdx.x;
    int i = blockIdx.x * 256 + tid;
    int v = (i < N_NODES) ? counts[i] : 0;
    s[tid] = v;
    __syncthreads();
    #pragma unroll
    for (int d = 1; d < 256; d <<= 1) {
        int t = (tid >= d) ? s[tid - d] : 0;
        __syncthreads();
        s[tid] += t;
        __syncthreads();
    }
    if (i < N_NODES) {
        int excl = blockBases[blockIdx.x] + s[tid] - v;
        off[i] = excl;
        cursor[i] = excl;
        if (i == N_NODES - 1) off[N_NODES] = excl + v;
    }
}

// epack.x = dst * 128 (byte offset of the node's 128 B fp16 row)
__global__ void scatter_kernel(const int* __restrict__ src, const int* __restrict__ dst,
                               const float* __restrict__ w,
                               int* __restrict__ cursor, int2* __restrict__ epack)
{
    int e = blockIdx.x * 256 + threadIdx.x;
    if (e < N_EDGES) {
        int s = src[e];
        int p = atomicAdd(&cursor[s], 1);
        epack[p] = make_int2(dst[e] << 7, __float_as_int(w[e]));
    }
}

// ---------------- Degree-sort (counting sort, 64 bins) ---------------------
__global__ void degHist_kernel(const int* __restrict__ counts, int* __restrict__ binCnt)
{
    int i = blockIdx.x * 256 + threadIdx.x;
    if (i < N_NODES) {
        int d = counts[i]; if (d > DBINS - 1) d = DBINS - 1;
        atomicAdd(&binCnt[d], 1);
    }
}

__global__ void degScan_kernel(const int* __restrict__ binCnt, int* __restrict__ binCur)
{
    if (threadIdx.x == 0) {
        int r = 0;
        for (int d = 0; d < DBINS; ++d) { binCur[d] = r; r += binCnt[d]; }
    }
}

__global__ void degScatter_kernel(const int* __restrict__ counts, int* __restrict__ binCur,
                                  int* __restrict__ node_order)
{
    int i = blockIdx.x * 256 + threadIdx.x;
    if (i < N_NODES) {
        int d = counts[i]; if (d > DBINS - 1) d = DBINS - 1;
        int p = atomicAdd(&binCur[d], 1);
        node_order[p] = i;
    }
}

// ---------------- Fused RK4 stage: degree-sorted 8-lane groups -------------
// Each lane owns 8 fp16 cols (uint4). 32 nodes/block, in degree-sorted order.
template<int STAGE>
__global__ __launch_bounds__(256) void stage_kernel(
    const int* __restrict__ node_order,
    const int* __restrict__ off, const int2* __restrict__ epack,
    const __half* __restrict__ zsH, const __half* __restrict__ zH,
    const float* __restrict__ zbF, const __half* __restrict__ x0H,
    const float* __restrict__ alpha, __half* __restrict__ accH,
    __half* __restrict__ outH, float* __restrict__ outZ, float cnext)
{
    int nidx = blockIdx.x * 32 + (threadIdx.x >> 3);
    if (nidx >= N_NODES) return;
    int node = node_order[nidx];
    int cb = (threadIdx.x & 7) << 4;   // byte offset of this lane's 16B slice
    int c  = cb >> 1;                  // fp16 element offset

    int jb = off[node], je = off[node + 1];
    const char* rdB = reinterpret_cast<const char*>(zsH);

    union H4 { uint4 u; __half2 h[4]; };

    float azA[8], azB[8];
    #pragma unroll
    for (int i = 0; i < 8; ++i) { azA[i] = 0.f; azB[i] = 0.f; }

#define ACC8(dst, V, W)                                                    \
    {                                                                      \
        float2 f0 = __half22float2((V).h[0]);                              \
        float2 f1 = __half22float2((V).h[1]);                              \
        float2 f2 = __half22float2((V).h[2]);                              \
        float2 f3 = __half22float2((V).h[3]);                              \
        dst[0] = fmaf(W, f0.x, dst[0]); dst[1] = fmaf(W, f0.y, dst[1]);    \
        dst[2] = fmaf(W, f1.x, dst[2]); dst[3] = fmaf(W, f1.y, dst[3]);    \
        dst[4] = fmaf(W, f2.x, dst[4]); dst[5] = fmaf(W, f2.y, dst[5]);    \
        dst[6] = fmaf(W, f3.x, dst[6]); dst[7] = fmaf(W, f3.y, dst[7]);    \
    }

    int j = jb;
    for (; j + 3 < je; j += 4) {
        int2 e0 = epack[j];
        int2 e1 = epack[j + 1];
        int2 e2 = epack[j + 2];
        int2 e3 = epack[j + 3];
        H4 v0, v1, v2, v3;
        v0.u = *reinterpret_cast<const uint4*>(rdB + (size_t)(unsigned)e0.x + cb);
        v1.u = *reinterpret_cast<const uint4*>(rdB + (size_t)(unsigned)e1.x + cb);
        v2.u = *reinterpret_cast<const uint4*>(rdB + (size_t)(unsigned)e2.x + cb);
        v3.u = *reinterpret_cast<const uint4*>(rdB + (size_t)(unsigned)e3.x + cb);
        float w0 = __int_as_float(e0.y), w1 = __int_as_float(e1.y);
        float w2 = __int_as_float(e2.y), w3 = __int_as_float(e3.y);
        ACC8(azA, v0, w0);
        ACC8(azB, v1, w1);
        ACC8(azA, v2, w2);
        ACC8(azB, v3, w3);
    }
    for (; j < je; ++j) {
        int2 e0 = epack[j];
        H4 v0;
        v0.u = *reinterpret_cast<const uint4*>(rdB + (size_t)(unsigned)e0.x + cb);
        float w0 = __int_as_float(e0.y);
        ACC8(azA, v0, w0);
    }
#undef ACC8

    float az[8];
    #pragma unroll
    for (int i = 0; i < 8; ++i) az[i] = azA[i] + azB[i];

    size_t idx = (size_t)node * H_DIM + c;
    H4 sr; sr.u = *reinterpret_cast<const uint4*>(zsH + idx);
    float s[8];
    {
        float2 f0 = __half22float2(sr.h[0]), f1 = __half22float2(sr.h[1]);
        float2 f2 = __half22float2(sr.h[2]), f3 = __half22float2(sr.h[3]);
        s[0] = f0.x; s[1] = f0.y; s[2] = f1.x; s[3] = f1.y;
        s[4] = f2.x; s[5] = f2.y; s[6] = f3.x; s[7] = f3.y;
    }
    H4 xr; xr.u = *reinterpret_cast<const uint4*>(x0H + idx);
    float xv[8];
    {
        float2 f0 = __half22float2(xr.h[0]), f1 = __half22float2(xr.h[1]);
        float2 f2 = __half22float2(xr.h[2]), f3 = __half22float2(xr.h[3]);
        xv[0] = f0.x; xv[1] = f0.y; xv[2] = f1.x; xv[3] = f1.y;
        xv[4] = f2.x; xv[5] = f2.y; xv[6] = f3.x; xv[7] = f3.y;
    }
    float a = 0.5f / (1.f + __expf(-alpha[node]));

    float k[8];
    #pragma unroll
    for (int i = 0; i < 8; ++i) k[i] = fmaf(a, az[i] - s[i], xv[i]);

    float o[8];
    if constexpr (STAGE == 0) {
        H4 aw;
        aw.h[0] = __float22half2_rn(make_float2(k[0], k[1]));
        aw.h[1] = __float22half2_rn(make_float2(k[2], k[3]));
        aw.h[2] = __float22half2_rn(make_float2(k[4], k[5]));
        aw.h[3] = __float22half2_rn(make_float2(k[6], k[7]));
        *reinterpret_cast<uint4*>(accH + idx) = aw.u;
        #pragma unroll
        for (int i = 0; i < 8; ++i) o[i] = fmaf(cnext, k[i], s[i]);
    } else if constexpr (STAGE == 1 || STAGE == 2) {
        H4 ar; ar.u = *reinterpret_cast<const uint4*>(accH + idx);
        float av[8];
        {
            float2 f0 = __half22float2(ar.h[0]), f1 = __half22float2(ar.h[1]);
            float2 f2 = __half22float2(ar.h[2]), f3 = __half22float2(ar.h[3]);
            av[0] = f0.x; av[1] = f0.y; av[2] = f1.x; av[3] = f1.y;
            av[4] = f2.x; av[5] = f2.y; av[6] = f3.x; av[7] = f3.y;
        }
        #pragma unroll
        for (int i = 0; i < 8; ++i) av[i] = fmaf(2.f, k[i], av[i]);
        H4 aw;
        aw.h[0] = __float22half2_rn(make_float2(av[0], av[1]));
        aw.h[1] = __float22half2_rn(make_float2(av[2], av[3]));
        aw.h[2] = __float22half2_rn(make_float2(av[4], av[5]));
        aw.h[3] = __float22half2_rn(make_float2(av[6], av[7]));
        *reinterpret_cast<uint4*>(accH + idx) = aw.u;
        H4 br; br.u = *reinterpret_cast<const uint4*>(zH + idx);
        float bv[8];
        {
            float2 f0 = __half22float2(br.h[0]), f1 = __half22float2(br.h[1]);
            float2 f2 = __half22float2(br.h[2]), f3 = __half22float2(br.h[3]);
            bv[0] = f0.x; bv[1] = f0.y; bv[2] = f1.x; bv[3] = f1.y;
            bv[4] = f2.x; bv[5] = f2.y; bv[6] = f3.x; bv[7] = f3.y;
        }
        #pragma unroll
        for (int i = 0; i < 8; ++i) o[i] = fmaf(cnext, k[i], bv[i]);
    } else {
        H4 ar; ar.u = *reinterpret_cast<const uint4*>(accH + idx);
        float av[8];
        {
            float2 f0 = __half22float2(ar.h[0]), f1 = __half22float2(ar.h[1]);
            float2 f2 = __half22float2(ar.h[2]), f3 = __half22float2(ar.h[3]);
            av[0] = f0.x; av[1] = f0.y; av[2] = f1.x; av[3] = f1.y;
            av[4] = f2.x; av[5] = f2.y; av[6] = f3.x; av[7] = f3.y;
        }
        float4 zb0 = *reinterpret_cast<const float4*>(zbF + idx);
        float4 zb1 = *reinterpret_cast<const float4*>(zbF + idx + 4);
        float zb[8] = {zb0.x, zb0.y, zb0.z, zb0.w, zb1.x, zb1.y, zb1.z, zb1.w};
        #pragma unroll
        for (int i = 0; i < 8; ++i) o[i] = fmaf(cnext, av[i] + k[i], zb[i]);
        float4 oz0 = make_float4(o[0], o[1], o[2], o[3]);
        float4 oz1 = make_float4(o[4], o[5], o[6], o[7]);
        *reinterpret_cast<float4*>(outZ + idx)     = oz0;
        *reinterpret_cast<float4*>(outZ + idx + 4) = oz1;
    }
    H4 sv;
    sv.h[0] = __float22half2_rn(make_float2(o[0], o[1]));
    sv.h[1] = __float22half2_rn(make_float2(o[2], o[3]));
    sv.h[2] = __float22half2_rn(make_float2(o[4], o[5]));
    sv.h[3] = __float22half2_rn(make_float2(o[6], o[7]));
    *reinterpret_cast<uint4*>(outH + idx) = sv.u;
}

// ---------------- Decoder: out = relu(z) @ m2_w + m2_b ----------------
__global__ __launch_bounds__(256) void decoder_kernel(
    const float* __restrict__ z, const float* __restrict__ W2,
    const float* __restrict__ b2, float* __restrict__ out)
{
    __shared__ float zsm[4][H_DIM];
    int lane = threadIdx.x & 63;
    int w    = threadIdx.x >> 6;
    int node = blockIdx.x * 4 + w;
    int ld   = node >= N_NODES ? N_NODES - 1 : node;
    float zv = z[(size_t)ld * H_DIM + lane];
    zsm[w][lane] = zv > 0.f ? zv : 0.f;
    __syncthreads();
    if (node < N_NODES && lane < C_OUT) {
        float acc = b2[lane];
        #pragma unroll
        for (int k = 0; k < H_DIM; ++k)
            acc = fmaf(zsm[w][k], W2[k * C_OUT + lane], acc);
        out[(size_t)node * C_OUT + lane] = acc;
    }
}

extern "C" void kernel_launch(void* const* d_in, const int* in_sizes, int n_in,
                              void* d_out, int out_size, void* d_ws, size_t ws_size,
                              hipStream_t stream)
{
    const float* x     = (const float*)d_in[0];
    const float* ew    = (const float*)d_in[1];
    const float* m1w   = (const float*)d_in[2];
    const float* m1b   = (const float*)d_in[3];
    const float* alpha = (const float*)d_in[4];
    const float* m2w   = (const float*)d_in[5];
    const float* m2b   = (const float*)d_in[6];
    const int*   esrc  = (const int*)d_in[7];
    const int*   edst  = (const int*)d_in[8];
    float* out = (float*)d_out;

    char* ws = (char*)d_ws;
    size_t o = 0;
    auto alloc = [&](size_t bytes) -> void* {
        void* p = ws + o;
        o = (o + bytes + 255) & ~(size_t)255;
        return p;
    };
    float*  z      = (float*)alloc((size_t)N_NODES * H_DIM * 4);
    __half* x0H    = (__half*)alloc((size_t)N_NODES * H_DIM * 2);
    __half* zH     = (__half*)alloc((size_t)N_NODES * H_DIM * 2);
    __half* ztAH   = (__half*)alloc((size_t)N_NODES * H_DIM * 2);
    __half* ztBH   = (__half*)alloc((size_t)N_NODES * H_DIM * 2);
    __half* accH   = (__half*)alloc((size_t)N_NODES * H_DIM * 2);
    __half* bfrag  = (__half*)alloc((size_t)KTILES * 4 * 64 * 8 * 2);
    int*    counts = (int*)alloc((size_t)N_NODES * 4);
    int*    off    = (int*)alloc((size_t)(N_NODES + 1) * 4);
    int*    cursor = (int*)alloc((size_t)N_NODES * 4);
    int*    bsums  = (int*)alloc((size_t)NB_SCAN * 4);
    int*    bbases = (int*)alloc((size_t)NB_SCAN * 4);
    int*    binCnt = (int*)alloc((size_t)DBINS * 4);
    int*    binCur = (int*)alloc((size_t)DBINS * 4);
    int*    nodeOrd= (int*)alloc((size_t)N_NODES * 4);
    int2*   epack  = (int2*)alloc((size_t)N_EDGES * 8);

    hipMemsetAsync(counts, 0, (size_t)N_NODES * 4, stream);
    hipMemsetAsync(binCnt, 0, (size_t)DBINS * 4, stream);
    hist_kernel<<<(N_EDGES + 255) / 256, 256, 0, stream>>>(esrc, counts);
    scanA_kernel<<<NB_SCAN, 256, 0, stream>>>(counts, bsums);
    scanB_kernel<<<1, 256, 0, stream>>>(bsums, bbases);
    scanC_kernel<<<NB_SCAN, 256, 0, stream>>>(counts, bbases, off, cursor);
    scatter_kernel<<<(N_EDGES + 255) / 256, 256, 0, stream>>>(esrc, edst, ew, cursor, epack);

    // degree-sorted node order (reuses counts = degrees)
    degHist_kernel<<<NB_SCAN, 256, 0, stream>>>(counts, binCnt);
    degScan_kernel<<<1, 64, 0, stream>>>(binCnt, binCur);
    degScatter_kernel<<<NB_SCAN, 256, 0, stream>>>(counts, binCur, nodeOrd);

    bfrag_kernel<<<(KTILES * 4 * 64 + 255) / 256, 256, 0, stream>>>(m1w, bfrag);
    encoder_kernel<<<(N_NODES + 31) / 32, 256, 0, stream>>>(x, bfrag, m1b, x0H, z, zH);

    const float dt = 1.0f / STEPS;
    int sgrid = (N_NODES + 31) / 32;
    for (int step = 0; step < STEPS; ++step) {
        stage_kernel<0><<<sgrid, 256, 0, stream>>>(nodeOrd, off, epack, zH,   zH, nullptr, x0H, alpha, accH, ztAH, nullptr, 0.5f * dt);
        stage_kernel<1><<<sgrid, 256, 0, stream>>>(nodeOrd, off, epack, ztAH, zH, nullptr, x0H, alpha, accH, ztBH, nullptr, 0.5f * dt);
        stage_kernel<2><<<sgrid, 256, 0, stream>>>(nodeOrd, off, epack, ztBH, zH, nullptr, x0H, alpha, accH, ztAH, nullptr, dt);
        stage_kernel<3><<<sgrid, 256, 0, stream>>>(nodeOrd, off, epack, ztAH, zH, z,       x0H, alpha, accH, zH,   z,       dt / 6.0f);
    }

    decoder_kernel<<<(N_NODES + 3) / 4, 256, 0, stream>>>(z, m2w, m2b, out);
}

// Round 11
// 439.982 us; speedup vs baseline: 1.6987x; 1.6987x over previous
//
#include <hip/hip_runtime.h>
#include <hip/hip_fp16.h>

#define N_NODES 50000
#define N_EDGES 600000
#define F_IN    500
#define H_DIM   64
#define C_OUT   40
#define STEPS   4
#define NB_SCAN ((N_NODES + 255) / 256)   // 196
#define KTILES  16                        // 512 k padded, 32 per MFMA
#define DBINS   64                        // degree bins for counting sort

using half8 = __attribute__((ext_vector_type(8))) _Float16;
using f32x4 = __attribute__((ext_vector_type(4))) float;

// ---------------- B-fragment precompute: W (500x64 f32) -> MFMA frags ------
__global__ __launch_bounds__(256) void bfrag_kernel(
    const float* __restrict__ W, __half* __restrict__ bfrag)
{
    int t = blockIdx.x * 256 + threadIdx.x;
    if (t >= KTILES * 4 * 64) return;
    int lane = t & 63;
    int c    = (t >> 6) & 3;
    int kt   = t >> 8;
    int col  = c * 16 + (lane & 15);
    int kb   = kt * 32 + (lane >> 4) * 8;
    union { uint4 u; __half h[8]; } v;
    #pragma unroll
    for (int j = 0; j < 8; ++j) {
        int k = kb + j;
        v.h[j] = (k < F_IN) ? __float2half(W[(size_t)k * H_DIM + col]) : __half(0.f);
    }
    *reinterpret_cast<uint4*>(bfrag + (size_t)t * 8) = v.u;
}

// ---------------- Encoder: MFMA GEMM, K-split pairs + full x prefetch ------
__global__ __launch_bounds__(256) void encoder_kernel(
    const float* __restrict__ x, const __half* __restrict__ bfrag,
    const float* __restrict__ b, __half* __restrict__ x0H,
    float* __restrict__ zF, __half* __restrict__ zH)
{
    __shared__ f32x4 red[2][64][4];   // 8 KB

    int wave = threadIdx.x >> 6;
    int lane = threadIdx.x & 63;
    int pair = wave >> 1;
    int half = wave & 1;
    int rowl = lane & 15;
    int kg   = lane >> 4;              // 0..3
    int r0   = blockIdx.x * 32 + pair * 16;

    int gr = r0 + rowl; if (gr >= N_NODES) gr = N_NODES - 1;
    const float* xrow = x + (size_t)gr * F_IN;
    const uint4* bf = reinterpret_cast<const uint4*>(bfrag);

    int ktb = half * 8;

    float4 xv[16];
    #pragma unroll
    for (int ki = 0; ki < 8; ++ki) {
        int k0 = (ktb + ki) * 32 + kg * 8;
        xv[2 * ki]     = make_float4(0.f, 0.f, 0.f, 0.f);
        xv[2 * ki + 1] = make_float4(0.f, 0.f, 0.f, 0.f);
        if (k0 + 4 <= F_IN) xv[2 * ki]     = *reinterpret_cast<const float4*>(xrow + k0);
        if (k0 + 8 <= F_IN) xv[2 * ki + 1] = *reinterpret_cast<const float4*>(xrow + k0 + 4);
    }

    f32x4 acc[4];
    #pragma unroll
    for (int c = 0; c < 4; ++c) acc[c] = (f32x4){0.f, 0.f, 0.f, 0.f};

    #pragma unroll
    for (int ki = 0; ki < 8; ++ki) {
        int kt = ktb + ki;
        float4 xa = xv[2 * ki], xb = xv[2 * ki + 1];
        half8 a;
        a[0] = (_Float16)xa.x; a[1] = (_Float16)xa.y;
        a[2] = (_Float16)xa.z; a[3] = (_Float16)xa.w;
        a[4] = (_Float16)xb.x; a[5] = (_Float16)xb.y;
        a[6] = (_Float16)xb.z; a[7] = (_Float16)xb.w;
        #pragma unroll
        for (int c = 0; c < 4; ++c) {
            union { uint4 u; half8 h; } bv;
            bv.u = bf[(size_t)(kt * 4 + c) * 64 + lane];
            acc[c] = __builtin_amdgcn_mfma_f32_16x16x32_f16(a, bv.h, acc[c], 0, 0, 0);
        }
    }

    if (half == 1) {
        #pragma unroll
        for (int c = 0; c < 4; ++c) red[pair][lane][c] = acc[c];
    }
    __syncthreads();
    if (half == 0) {
        #pragma unroll
        for (int c = 0; c < 4; ++c) {
            f32x4 r = red[pair][lane][c];
            acc[c][0] += r[0]; acc[c][1] += r[1];
            acc[c][2] += r[2]; acc[c][3] += r[3];
        }
        #pragma unroll
        for (int c = 0; c < 4; ++c) {
            int col = c * 16 + rowl;
            float bias = b[col];
            #pragma unroll
            for (int r = 0; r < 4; ++r) {
                int grow = r0 + kg * 4 + r;
                if (grow < N_NODES) {
                    float v = acc[c][r] + bias;
                    size_t idx = (size_t)grow * H_DIM + col;
                    zF[idx]  = v;
                    __half hv = __float2half(v);
                    zH[idx]  = hv;
                    x0H[idx] = hv;
                }
            }
        }
    }
}

// ---------------- CSR build ----------------
__global__ void hist_kernel(const int* __restrict__ src, int* __restrict__ counts)
{
    int e = blockIdx.x * 256 + threadIdx.x;
    if (e < N_EDGES) atomicAdd(&counts[src[e]], 1);
}

__global__ __launch_bounds__(256) void scanA_kernel(
    const int* __restrict__ counts, int* __restrict__ blockSums)
{
    __shared__ int red[256];
    int i = blockIdx.x * 256 + threadIdx.x;
    red[threadIdx.x] = (i < N_NODES) ? counts[i] : 0;
    __syncthreads();
    #pragma unroll
    for (int s = 128; s > 0; s >>= 1) {
        if (threadIdx.x < s) red[threadIdx.x] += red[threadIdx.x + s];
        __syncthreads();
    }
    if (threadIdx.x == 0) blockSums[blockIdx.x] = red[0];
}

__global__ __launch_bounds__(256) void scanB_kernel(
    const int* __restrict__ blockSums, int* __restrict__ blockBases)
{
    __shared__ int s[256];
    int tid = threadIdx.x;
    int v = (tid < NB_SCAN) ? blockSums[tid] : 0;
    s[tid] = v;
    __syncthreads();
    #pragma unroll
    for (int d = 1; d < 256; d <<= 1) {
        int t = (tid >= d) ? s[tid - d] : 0;
        __syncthreads();
        s[tid] += t;
        __syncthreads();
    }
    if (tid < NB_SCAN) blockBases[tid] = s[tid] - v;
}

__global__ __launch_bounds__(256) void scanC_kernel(
    const int* __restrict__ counts, const int* __restrict__ blockBases,
    int* __restrict__ off, int* __restrict__ cursor)
{
    __shared__ int s[256];
    int tid = threadIdx.x;
    int i = blockIdx.x * 256 + tid;
    int v = (i < N_NODES) ? counts[i] : 0;
    s[tid] = v;
    __syncthreads();
    #pragma unroll
    for (int d = 1; d < 256; d <<= 1) {
        int t = (tid >= d) ? s[tid - d] : 0;
        __syncthreads();
        s[tid] += t;
        __syncthreads();
    }
    if (i < N_NODES) {
        int excl = blockBases[blockIdx.x] + s[tid] - v;
        off[i] = excl;
        cursor[i] = excl;
        if (i == N_NODES - 1) off[N_NODES] = excl + v;
    }
}

// epack.x = dst * 128 (byte offset of the node's 128 B fp16 row)
__global__ void scatter_kernel(const int* __restrict__ src, const int* __restrict__ dst,
                               const float* __restrict__ w,
                               int* __restrict__ cursor, int2* __restrict__ epack)
{
    int e = blockIdx.x * 256 + threadIdx.x;
    if (e < N_EDGES) {
        int s = src[e];
        int p = atomicAdd(&cursor[s], 1);
        epack[p] = make_int2(dst[e] << 7, __float_as_int(w[e]));
    }
}

// ---------------- Degree-sort (contention-free counting sort) --------------
// A: per-block LDS histogram -> blockBinCnt[b][DBINS]
__global__ __launch_bounds__(256) void blockHist_kernel(
    const int* __restrict__ counts, int* __restrict__ blockBinCnt)
{
    __shared__ int lh[DBINS];
    int t = threadIdx.x;
    if (t < DBINS) lh[t] = 0;
    __syncthreads();
    int i = blockIdx.x * 256 + t;
    if (i < N_NODES) {
        int d = counts[i]; if (d > DBINS - 1) d = DBINS - 1;
        atomicAdd(&lh[d], 1);
    }
    __syncthreads();
    if (t < DBINS) blockBinCnt[blockIdx.x * DBINS + t] = lh[t];
}

// B: baseMat[b][d] = binStart[d] + sum_{b'<b} blockBinCnt[b'][d]  (1 block, 64 thr)
__global__ __launch_bounds__(64) void degBase_kernel(
    const int* __restrict__ blockBinCnt, int* __restrict__ baseMat)
{
    __shared__ int tot[DBINS];
    __shared__ int start[DBINS];
    int d = threadIdx.x;
    int s = 0;
    for (int b = 0; b < NB_SCAN; ++b) s += blockBinCnt[b * DBINS + d];
    tot[d] = s;
    __syncthreads();
    if (d == 0) {
        int r = 0;
        for (int q = 0; q < DBINS; ++q) { start[q] = r; r += tot[q]; }
    }
    __syncthreads();
    int r = start[d];
    for (int b = 0; b < NB_SCAN; ++b) {
        baseMat[b * DBINS + d] = r;
        r += blockBinCnt[b * DBINS + d];
    }
}

// C: scatter via LDS cursors (intra-block contention only)
__global__ __launch_bounds__(256) void degScatter_kernel(
    const int* __restrict__ counts, const int* __restrict__ baseMat,
    int* __restrict__ node_order)
{
    __shared__ int lcur[DBINS];
    int t = threadIdx.x;
    if (t < DBINS) lcur[t] = baseMat[blockIdx.x * DBINS + t];
    __syncthreads();
    int i = blockIdx.x * 256 + t;
    if (i < N_NODES) {
        int d = counts[i]; if (d > DBINS - 1) d = DBINS - 1;
        int p = atomicAdd(&lcur[d], 1);
        node_order[p] = i;
    }
}

// ---------------- Fused RK4 stage: degree-sorted 8-lane groups -------------
template<int STAGE>
__global__ __launch_bounds__(256) void stage_kernel(
    const int* __restrict__ node_order,
    const int* __restrict__ off, const int2* __restrict__ epack,
    const __half* __restrict__ zsH, const __half* __restrict__ zH,
    const float* __restrict__ zbF, const __half* __restrict__ x0H,
    const float* __restrict__ alpha, __half* __restrict__ accH,
    __half* __restrict__ outH, float* __restrict__ outZ, float cnext)
{
    int nidx = blockIdx.x * 32 + (threadIdx.x >> 3);
    if (nidx >= N_NODES) return;
    int node = node_order[nidx];
    int cb = (threadIdx.x & 7) << 4;   // byte offset of this lane's 16B slice
    int c  = cb >> 1;                  // fp16 element offset

    int jb = off[node], je = off[node + 1];
    const char* rdB = reinterpret_cast<const char*>(zsH);

    union H4 { uint4 u; __half2 h[4]; };

    float azA[8], azB[8];
    #pragma unroll
    for (int i = 0; i < 8; ++i) { azA[i] = 0.f; azB[i] = 0.f; }

#define ACC8(dst, V, W)                                                    \
    {                                                                      \
        float2 f0 = __half22float2((V).h[0]);                              \
        float2 f1 = __half22float2((V).h[1]);                              \
        float2 f2 = __half22float2((V).h[2]);                              \
        float2 f3 = __half22float2((V).h[3]);                              \
        dst[0] = fmaf(W, f0.x, dst[0]); dst[1] = fmaf(W, f0.y, dst[1]);    \
        dst[2] = fmaf(W, f1.x, dst[2]); dst[3] = fmaf(W, f1.y, dst[3]);    \
        dst[4] = fmaf(W, f2.x, dst[4]); dst[5] = fmaf(W, f2.y, dst[5]);    \
        dst[6] = fmaf(W, f3.x, dst[6]); dst[7] = fmaf(W, f3.y, dst[7]);    \
    }

    int j = jb;
    for (; j + 3 < je; j += 4) {
        int2 e0 = epack[j];
        int2 e1 = epack[j + 1];
        int2 e2 = epack[j + 2];
        int2 e3 = epack[j + 3];
        H4 v0, v1, v2, v3;
        v0.u = *reinterpret_cast<const uint4*>(rdB + (size_t)(unsigned)e0.x + cb);
        v1.u = *reinterpret_cast<const uint4*>(rdB + (size_t)(unsigned)e1.x + cb);
        v2.u = *reinterpret_cast<const uint4*>(rdB + (size_t)(unsigned)e2.x + cb);
        v3.u = *reinterpret_cast<const uint4*>(rdB + (size_t)(unsigned)e3.x + cb);
        float w0 = __int_as_float(e0.y), w1 = __int_as_float(e1.y);
        float w2 = __int_as_float(e2.y), w3 = __int_as_float(e3.y);
        ACC8(azA, v0, w0);
        ACC8(azB, v1, w1);
        ACC8(azA, v2, w2);
        ACC8(azB, v3, w3);
    }
    for (; j < je; ++j) {
        int2 e0 = epack[j];
        H4 v0;
        v0.u = *reinterpret_cast<const uint4*>(rdB + (size_t)(unsigned)e0.x + cb);
        float w0 = __int_as_float(e0.y);
        ACC8(azA, v0, w0);
    }
#undef ACC8

    float az[8];
    #pragma unroll
    for (int i = 0; i < 8; ++i) az[i] = azA[i] + azB[i];

    size_t idx = (size_t)node * H_DIM + c;
    H4 sr; sr.u = *reinterpret_cast<const uint4*>(zsH + idx);
    float s[8];
    {
        float2 f0 = __half22float2(sr.h[0]), f1 = __half22float2(sr.h[1]);
        float2 f2 = __half22float2(sr.h[2]), f3 = __half22float2(sr.h[3]);
        s[0] = f0.x; s[1] = f0.y; s[2] = f1.x; s[3] = f1.y;
        s[4] = f2.x; s[5] = f2.y; s[6] = f3.x; s[7] = f3.y;
    }
    H4 xr; xr.u = *reinterpret_cast<const uint4*>(x0H + idx);
    float xv[8];
    {
        float2 f0 = __half22float2(xr.h[0]), f1 = __half22float2(xr.h[1]);
        float2 f2 = __half22float2(xr.h[2]), f3 = __half22float2(xr.h[3]);
        xv[0] = f0.x; xv[1] = f0.y; xv[2] = f1.x; xv[3] = f1.y;
        xv[4] = f2.x; xv[5] = f2.y; xv[6] = f3.x; xv[7] = f3.y;
    }
    float a = 0.5f / (1.f + __expf(-alpha[node]));

    float k[8];
    #pragma unroll
    for (int i = 0; i < 8; ++i) k[i] = fmaf(a, az[i] - s[i], xv[i]);

    float o[8];
    if constexpr (STAGE == 0) {
        H4 aw;
        aw.h[0] = __float22half2_rn(make_float2(k[0], k[1]));
        aw.h[1] = __float22half2_rn(make_float2(k[2], k[3]));
        aw.h[2] = __float22half2_rn(make_float2(k[4], k[5]));
        aw.h[3] = __float22half2_rn(make_float2(k[6], k[7]));
        *reinterpret_cast<uint4*>(accH + idx) = aw.u;
        #pragma unroll
        for (int i = 0; i < 8; ++i) o[i] = fmaf(cnext, k[i], s[i]);
    } else if constexpr (STAGE == 1 || STAGE == 2) {
        H4 ar; ar.u = *reinterpret_cast<const uint4*>(accH + idx);
        float av[8];
        {
            float2 f0 = __half22float2(ar.h[0]), f1 = __half22float2(ar.h[1]);
            float2 f2 = __half22float2(ar.h[2]), f3 = __half22float2(ar.h[3]);
            av[0] = f0.x; av[1] = f0.y; av[2] = f1.x; av[3] = f1.y;
            av[4] = f2.x; av[5] = f2.y; av[6] = f3.x; av[7] = f3.y;
        }
        #pragma unroll
        for (int i = 0; i < 8; ++i) av[i] = fmaf(2.f, k[i], av[i]);
        H4 aw;
        aw.h[0] = __float22half2_rn(make_float2(av[0], av[1]));
        aw.h[1] = __float22half2_rn(make_float2(av[2], av[3]));
        aw.h[2] = __float22half2_rn(make_float2(av[4], av[5]));
        aw.h[3] = __float22half2_rn(make_float2(av[6], av[7]));
        *reinterpret_cast<uint4*>(accH + idx) = aw.u;
        H4 br; br.u = *reinterpret_cast<const uint4*>(zH + idx);
        float bv[8];
        {
            float2 f0 = __half22float2(br.h[0]), f1 = __half22float2(br.h[1]);
            float2 f2 = __half22float2(br.h[2]), f3 = __half22float2(br.h[3]);
            bv[0] = f0.x; bv[1] = f0.y; bv[2] = f1.x; bv[3] = f1.y;
            bv[4] = f2.x; bv[5] = f2.y; bv[6] = f3.x; bv[7] = f3.y;
        }
        #pragma unroll
        for (int i = 0; i < 8; ++i) o[i] = fmaf(cnext, k[i], bv[i]);
    } else {
        H4 ar; ar.u = *reinterpret_cast<const uint4*>(accH + idx);
        float av[8];
        {
            float2 f0 = __half22float2(ar.h[0]), f1 = __half22float2(ar.h[1]);
            float2 f2 = __half22float2(ar.h[2]), f3 = __half22float2(ar.h[3]);
            av[0] = f0.x; av[1] = f0.y; av[2] = f1.x; av[3] = f1.y;
            av[4] = f2.x; av[5] = f2.y; av[6] = f3.x; av[7] = f3.y;
        }
        float4 zb0 = *reinterpret_cast<const float4*>(zbF + idx);
        float4 zb1 = *reinterpret_cast<const float4*>(zbF + idx + 4);
        float zb[8] = {zb0.x, zb0.y, zb0.z, zb0.w, zb1.x, zb1.y, zb1.z, zb1.w};
        #pragma unroll
        for (int i = 0; i < 8; ++i) o[i] = fmaf(cnext, av[i] + k[i], zb[i]);
        float4 oz0 = make_float4(o[0], o[1], o[2], o[3]);
        float4 oz1 = make_float4(o[4], o[5], o[6], o[7]);
        *reinterpret_cast<float4*>(outZ + idx)     = oz0;
        *reinterpret_cast<float4*>(outZ + idx + 4) = oz1;
    }
    H4 sv;
    sv.h[0] = __float22half2_rn(make_float2(o[0], o[1]));
    sv.h[1] = __float22half2_rn(make_float2(o[2], o[3]));
    sv.h[2] = __float22half2_rn(make_float2(o[4], o[5]));
    sv.h[3] = __float22half2_rn(make_float2(o[6], o[7]));
    *reinterpret_cast<uint4*>(outH + idx) = sv.u;
}

// ---------------- Decoder: out = relu(z) @ m2_w + m2_b ----------------
__global__ __launch_bounds__(256) void decoder_kernel(
    const float* __restrict__ z, const float* __restrict__ W2,
    const float* __restrict__ b2, float* __restrict__ out)
{
    __shared__ float zsm[4][H_DIM];
    int lane = threadIdx.x & 63;
    int w    = threadIdx.x >> 6;
    int node = blockIdx.x * 4 + w;
    int ld   = node >= N_NODES ? N_NODES - 1 : node;
    float zv = z[(size_t)ld * H_DIM + lane];
    zsm[w][lane] = zv > 0.f ? zv : 0.f;
    __syncthreads();
    if (node < N_NODES && lane < C_OUT) {
        float acc = b2[lane];
        #pragma unroll
        for (int k = 0; k < H_DIM; ++k)
            acc = fmaf(zsm[w][k], W2[k * C_OUT + lane], acc);
        out[(size_t)node * C_OUT + lane] = acc;
    }
}

extern "C" void kernel_launch(void* const* d_in, const int* in_sizes, int n_in,
                              void* d_out, int out_size, void* d_ws, size_t ws_size,
                              hipStream_t stream)
{
    const float* x     = (const float*)d_in[0];
    const float* ew    = (const float*)d_in[1];
    const float* m1w   = (const float*)d_in[2];
    const float* m1b   = (const float*)d_in[3];
    const float* alpha = (const float*)d_in[4];
    const float* m2w   = (const float*)d_in[5];
    const float* m2b   = (const float*)d_in[6];
    const int*   esrc  = (const int*)d_in[7];
    const int*   edst  = (const int*)d_in[8];
    float* out = (float*)d_out;

    char* ws = (char*)d_ws;
    size_t o = 0;
    auto alloc = [&](size_t bytes) -> void* {
        void* p = ws + o;
        o = (o + bytes + 255) & ~(size_t)255;
        return p;
    };
    float*  z      = (float*)alloc((size_t)N_NODES * H_DIM * 4);
    __half* x0H    = (__half*)alloc((size_t)N_NODES * H_DIM * 2);
    __half* zH     = (__half*)alloc((size_t)N_NODES * H_DIM * 2);
    __half* ztAH   = (__half*)alloc((size_t)N_NODES * H_DIM * 2);
    __half* ztBH   = (__half*)alloc((size_t)N_NODES * H_DIM * 2);
    __half* accH   = (__half*)alloc((size_t)N_NODES * H_DIM * 2);
    __half* bfrag  = (__half*)alloc((size_t)KTILES * 4 * 64 * 8 * 2);
    int*    counts = (int*)alloc((size_t)N_NODES * 4);
    int*    off    = (int*)alloc((size_t)(N_NODES + 1) * 4);
    int*    cursor = (int*)alloc((size_t)N_NODES * 4);
    int*    bsums  = (int*)alloc((size_t)NB_SCAN * 4);
    int*    bbases = (int*)alloc((size_t)NB_SCAN * 4);
    int*    bbc    = (int*)alloc((size_t)NB_SCAN * DBINS * 4);   // blockBinCnt
    int*    bmat   = (int*)alloc((size_t)NB_SCAN * DBINS * 4);   // baseMat
    int*    nodeOrd= (int*)alloc((size_t)N_NODES * 4);
    int2*   epack  = (int2*)alloc((size_t)N_EDGES * 8);

    hipMemsetAsync(counts, 0, (size_t)N_NODES * 4, stream);
    hist_kernel<<<(N_EDGES + 255) / 256, 256, 0, stream>>>(esrc, counts);
    scanA_kernel<<<NB_SCAN, 256, 0, stream>>>(counts, bsums);
    scanB_kernel<<<1, 256, 0, stream>>>(bsums, bbases);
    scanC_kernel<<<NB_SCAN, 256, 0, stream>>>(counts, bbases, off, cursor);
    scatter_kernel<<<(N_EDGES + 255) / 256, 256, 0, stream>>>(esrc, edst, ew, cursor, epack);

    // contention-free degree sort
    blockHist_kernel<<<NB_SCAN, 256, 0, stream>>>(counts, bbc);
    degBase_kernel<<<1, 64, 0, stream>>>(bbc, bmat);
    degScatter_kernel<<<NB_SCAN, 256, 0, stream>>>(counts, bmat, nodeOrd);

    bfrag_kernel<<<(KTILES * 4 * 64 + 255) / 256, 256, 0, stream>>>(m1w, bfrag);
    encoder_kernel<<<(N_NODES + 31) / 32, 256, 0, stream>>>(x, bfrag, m1b, x0H, z, zH);

    const float dt = 1.0f / STEPS;
    int sgrid = (N_NODES + 31) / 32;
    for (int step = 0; step < STEPS; ++step) {
        stage_kernel<0><<<sgrid, 256, 0, stream>>>(nodeOrd, off, epack, zH,   zH, nullptr, x0H, alpha, accH, ztAH, nullptr, 0.5f * dt);
        stage_kernel<1><<<sgrid, 256, 0, stream>>>(nodeOrd, off, epack, ztAH, zH, nullptr, x0H, alpha, accH, ztBH, nullptr, 0.5f * dt);
        stage_kernel<2><<<sgrid, 256, 0, stream>>>(nodeOrd, off, epack, ztBH, zH, nullptr, x0H, alpha, accH, ztAH, nullptr, dt);
        stage_kernel<3><<<sgrid, 256, 0, stream>>>(nodeOrd, off, epack, ztAH, zH, z,       x0H, alpha, accH, zH,   z,       dt / 6.0f);
    }

    decoder_kernel<<<(N_NODES + 3) / 4, 256, 0, stream>>>(z, m2w, m2b, out);
}

// Round 12
// 423.985 us; speedup vs baseline: 1.7628x; 1.0377x over previous
//
#include <hip/hip_runtime.h>
#include <hip/hip_fp16.h>

#define N_NODES 50000
#define N_EDGES 600000
#define F_IN    500
#define H_DIM   64
#define C_OUT   40
#define STEPS   4
#define NB_SCAN ((N_NODES + 255) / 256)   // 196
#define KTILES  16                        // 512 k padded, 32 per MFMA
#define DBINS   64                        // degree bins for counting sort

using half8 = __attribute__((ext_vector_type(8))) _Float16;
using f32x4 = __attribute__((ext_vector_type(4))) float;

// ---------------- B-fragment precompute: W (500x64 f32) -> MFMA frags ------
__global__ __launch_bounds__(256) void bfrag_kernel(
    const float* __restrict__ W, __half* __restrict__ bfrag)
{
    int t = blockIdx.x * 256 + threadIdx.x;
    if (t >= KTILES * 4 * 64) return;
    int lane = t & 63;
    int c    = (t >> 6) & 3;
    int kt   = t >> 8;
    int col  = c * 16 + (lane & 15);
    int kb   = kt * 32 + (lane >> 4) * 8;
    union { uint4 u; __half h[8]; } v;
    #pragma unroll
    for (int j = 0; j < 8; ++j) {
        int k = kb + j;
        v.h[j] = (k < F_IN) ? __float2half(W[(size_t)k * H_DIM + col]) : __half(0.f);
    }
    *reinterpret_cast<uint4*>(bfrag + (size_t)t * 8) = v.u;
}

// ---------------- Encoder: MFMA GEMM; rows written PERMUTED ---------------
__global__ __launch_bounds__(256) void encoder_kernel(
    const float* __restrict__ x, const __half* __restrict__ bfrag,
    const float* __restrict__ b, const int* __restrict__ invOrd,
    __half* __restrict__ x0H, float* __restrict__ zF, __half* __restrict__ zH)
{
    __shared__ f32x4 red[2][64][4];   // 8 KB

    int wave = threadIdx.x >> 6;
    int lane = threadIdx.x & 63;
    int pair = wave >> 1;
    int half = wave & 1;
    int rowl = lane & 15;
    int kg   = lane >> 4;              // 0..3
    int r0   = blockIdx.x * 32 + pair * 16;

    int gr = r0 + rowl; if (gr >= N_NODES) gr = N_NODES - 1;
    const float* xrow = x + (size_t)gr * F_IN;
    const uint4* bf = reinterpret_cast<const uint4*>(bfrag);

    int ktb = half * 8;

    float4 xv[16];
    #pragma unroll
    for (int ki = 0; ki < 8; ++ki) {
        int k0 = (ktb + ki) * 32 + kg * 8;
        xv[2 * ki]     = make_float4(0.f, 0.f, 0.f, 0.f);
        xv[2 * ki + 1] = make_float4(0.f, 0.f, 0.f, 0.f);
        if (k0 + 4 <= F_IN) xv[2 * ki]     = *reinterpret_cast<const float4*>(xrow + k0);
        if (k0 + 8 <= F_IN) xv[2 * ki + 1] = *reinterpret_cast<const float4*>(xrow + k0 + 4);
    }

    f32x4 acc[4];
    #pragma unroll
    for (int c = 0; c < 4; ++c) acc[c] = (f32x4){0.f, 0.f, 0.f, 0.f};

    #pragma unroll
    for (int ki = 0; ki < 8; ++ki) {
        int kt = ktb + ki;
        float4 xa = xv[2 * ki], xb = xv[2 * ki + 1];
        half8 a;
        a[0] = (_Float16)xa.x; a[1] = (_Float16)xa.y;
        a[2] = (_Float16)xa.z; a[3] = (_Float16)xa.w;
        a[4] = (_Float16)xb.x; a[5] = (_Float16)xb.y;
        a[6] = (_Float16)xb.z; a[7] = (_Float16)xb.w;
        #pragma unroll
        for (int c = 0; c < 4; ++c) {
            union { uint4 u; half8 h; } bv;
            bv.u = bf[(size_t)(kt * 4 + c) * 64 + lane];
            acc[c] = __builtin_amdgcn_mfma_f32_16x16x32_f16(a, bv.h, acc[c], 0, 0, 0);
        }
    }

    if (half == 1) {
        #pragma unroll
        for (int c = 0; c < 4; ++c) red[pair][lane][c] = acc[c];
    }
    __syncthreads();
    if (half == 0) {
        #pragma unroll
        for (int c = 0; c < 4; ++c) {
            f32x4 r = red[pair][lane][c];
            acc[c][0] += r[0]; acc[c][1] += r[1];
            acc[c][2] += r[2]; acc[c][3] += r[3];
        }
        #pragma unroll
        for (int r = 0; r < 4; ++r) {
            int grow = r0 + kg * 4 + r;
            if (grow < N_NODES) {
                int prow = invOrd[grow];
                #pragma unroll
                for (int c = 0; c < 4; ++c) {
                    int col = c * 16 + rowl;
                    float v = acc[c][r] + b[col];
                    size_t idx = (size_t)prow * H_DIM + col;
                    zF[idx]  = v;
                    __half hv = __float2half(v);
                    zH[idx]  = hv;
                    x0H[idx] = hv;
                }
            }
        }
    }
}

// ---------------- CSR build ----------------
__global__ void hist_kernel(const int* __restrict__ src, int* __restrict__ counts)
{
    int e = blockIdx.x * 256 + threadIdx.x;
    if (e < N_EDGES) atomicAdd(&counts[src[e]], 1);
}

__global__ __launch_bounds__(256) void scanA_kernel(
    const int* __restrict__ counts, int* __restrict__ blockSums)
{
    __shared__ int red[256];
    int i = blockIdx.x * 256 + threadIdx.x;
    red[threadIdx.x] = (i < N_NODES) ? counts[i] : 0;
    __syncthreads();
    #pragma unroll
    for (int s = 128; s > 0; s >>= 1) {
        if (threadIdx.x < s) red[threadIdx.x] += red[threadIdx.x + s];
        __syncthreads();
    }
    if (threadIdx.x == 0) blockSums[blockIdx.x] = red[0];
}

__global__ __launch_bounds__(256) void scanB_kernel(
    const int* __restrict__ blockSums, int* __restrict__ blockBases)
{
    __shared__ int s[256];
    int tid = threadIdx.x;
    int v = (tid < NB_SCAN) ? blockSums[tid] : 0;
    s[tid] = v;
    __syncthreads();
    #pragma unroll
    for (int d = 1; d < 256; d <<= 1) {
        int t = (tid >= d) ? s[tid - d] : 0;
        __syncthreads();
        s[tid] += t;
        __syncthreads();
    }
    if (tid < NB_SCAN) blockBases[tid] = s[tid] - v;
}

__global__ __launch_bounds__(256) void scanC_kernel(
    const int* __restrict__ counts, const int* __restrict__ blockBases,
    int* __restrict__ off, int* __restrict__ cursor)
{
    __shared__ int s[256];
    int tid = threadIdx.x;
    int i = blockIdx.x * 256 + tid;
    int v = (i < N_NODES) ? counts[i] : 0;
    s[tid] = v;
    __syncthreads();
    #pragma unroll
    for (int d = 1; d < 256; d <<= 1) {
        int t = (tid >= d) ? s[tid - d] : 0;
        __syncthreads();
        s[tid] += t;
        __syncthreads();
    }
    if (i < N_NODES) {
        int excl = blockBases[blockIdx.x] + s[tid] - v;
        off[i] = excl;
        cursor[i] = excl;
        if (i == N_NODES - 1) off[N_NODES] = excl + v;
    }
}

// ---------------- Degree-sort (contention-free counting sort) --------------
__global__ __launch_bounds__(256) void blockHist_kernel(
    const int* __restrict__ counts, int* __restrict__ blockBinCnt)
{
    __shared__ int lh[DBINS];
    int t = threadIdx.x;
    if (t < DBINS) lh[t] = 0;
    __syncthreads();
    int i = blockIdx.x * 256 + t;
    if (i < N_NODES) {
        int d = counts[i]; if (d > DBINS - 1) d = DBINS - 1;
        atomicAdd(&lh[d], 1);
    }
    __syncthreads();
    if (t < DBINS) blockBinCnt[blockIdx.x * DBINS + t] = lh[t];
}

__global__ __launch_bounds__(64) void degBase_kernel(
    const int* __restrict__ blockBinCnt, int* __restrict__ baseMat)
{
    __shared__ int tot[DBINS];
    __shared__ int start[DBINS];
    int d = threadIdx.x;
    int s = 0;
    for (int b = 0; b < NB_SCAN; ++b) s += blockBinCnt[b * DBINS + d];
    tot[d] = s;
    __syncthreads();
    if (d == 0) {
        int r = 0;
        for (int q = 0; q < DBINS; ++q) { start[q] = r; r += tot[q]; }
    }
    __syncthreads();
    int r = start[d];
    for (int b = 0; b < NB_SCAN; ++b) {
        baseMat[b * DBINS + d] = r;
        r += blockBinCnt[b * DBINS + d];
    }
}

__global__ __launch_bounds__(256) void degScatter_kernel(
    const int* __restrict__ counts, const int* __restrict__ baseMat,
    int* __restrict__ node_order)
{
    __shared__ int lcur[DBINS];
    int t = threadIdx.x;
    if (t < DBINS) lcur[t] = baseMat[blockIdx.x * DBINS + t];
    __syncthreads();
    int i = blockIdx.x * 256 + t;
    if (i < N_NODES) {
        int d = counts[i]; if (d > DBINS - 1) d = DBINS - 1;
        int p = atomicAdd(&lcur[d], 1);
        node_order[p] = i;
    }
}

// invOrd[old] = new
__global__ void invOrd_kernel(const int* __restrict__ nodeOrd, int* __restrict__ invOrd)
{
    int i = blockIdx.x * 256 + threadIdx.x;
    if (i < N_NODES) invOrd[nodeOrd[i]] = i;
}

// per-new-id metadata: CSR range + alpha coefficient
__global__ void permMeta_kernel(const int* __restrict__ nodeOrd,
                                const int* __restrict__ off,
                                const float* __restrict__ alpha,
                                int* __restrict__ jbArr, int* __restrict__ jeArr,
                                float* __restrict__ acoArr)
{
    int i = blockIdx.x * 256 + threadIdx.x;
    if (i < N_NODES) {
        int old = nodeOrd[i];
        jbArr[i]  = off[old];
        jeArr[i]  = off[old + 1];
        acoArr[i] = 0.5f / (1.f + __expf(-alpha[old]));
    }
}

// epack.x = invOrd[dst] * 128 (byte offset of permuted fp16 row)
__global__ void scatter_kernel(const int* __restrict__ src, const int* __restrict__ dst,
                               const float* __restrict__ w, const int* __restrict__ invOrd,
                               int* __restrict__ cursor, int2* __restrict__ epack)
{
    int e = blockIdx.x * 256 + threadIdx.x;
    if (e < N_EDGES) {
        int s = src[e];
        int p = atomicAdd(&cursor[s], 1);
        epack[p] = make_int2(invOrd[dst[e]] << 7, __float_as_int(w[e]));
    }
}

// ---------------- Fused RK4 stage: permuted space, sequential ids ----------
// Each lane owns 8 fp16 cols (uint4). 32 nodes/block; waves have uniform degree.
template<int STAGE>
__global__ __launch_bounds__(256) void stage_kernel(
    const int* __restrict__ jbArr, const int* __restrict__ jeArr,
    const float* __restrict__ acoArr, const int2* __restrict__ epack,
    const __half* __restrict__ zsH, const __half* __restrict__ zH,
    const float* __restrict__ zbF, const __half* __restrict__ x0H,
    __half* __restrict__ accH,
    __half* __restrict__ outH, float* __restrict__ outZ, float cnext)
{
    int nidx = blockIdx.x * 32 + (threadIdx.x >> 3);
    if (nidx >= N_NODES) return;
    int cb = (threadIdx.x & 7) << 4;   // byte offset of this lane's 16B slice
    int c  = cb >> 1;                  // fp16 element offset

    int jb = jbArr[nidx], je = jeArr[nidx];
    const char* rdB = reinterpret_cast<const char*>(zsH);

    union H4 { uint4 u; __half2 h[4]; };

    float azA[8], azB[8];
    #pragma unroll
    for (int i = 0; i < 8; ++i) { azA[i] = 0.f; azB[i] = 0.f; }

#define ACC8(dst, V, W)                                                    \
    {                                                                      \
        float2 f0 = __half22float2((V).h[0]);                              \
        float2 f1 = __half22float2((V).h[1]);                              \
        float2 f2 = __half22float2((V).h[2]);                              \
        float2 f3 = __half22float2((V).h[3]);                              \
        dst[0] = fmaf(W, f0.x, dst[0]); dst[1] = fmaf(W, f0.y, dst[1]);    \
        dst[2] = fmaf(W, f1.x, dst[2]); dst[3] = fmaf(W, f1.y, dst[3]);    \
        dst[4] = fmaf(W, f2.x, dst[4]); dst[5] = fmaf(W, f2.y, dst[5]);    \
        dst[6] = fmaf(W, f3.x, dst[6]); dst[7] = fmaf(W, f3.y, dst[7]);    \
    }

    int j = jb;
    for (; j + 3 < je; j += 4) {
        int2 e0 = epack[j];
        int2 e1 = epack[j + 1];
        int2 e2 = epack[j + 2];
        int2 e3 = epack[j + 3];
        H4 v0, v1, v2, v3;
        v0.u = *reinterpret_cast<const uint4*>(rdB + (size_t)(unsigned)e0.x + cb);
        v1.u = *reinterpret_cast<const uint4*>(rdB + (size_t)(unsigned)e1.x + cb);
        v2.u = *reinterpret_cast<const uint4*>(rdB + (size_t)(unsigned)e2.x + cb);
        v3.u = *reinterpret_cast<const uint4*>(rdB + (size_t)(unsigned)e3.x + cb);
        float w0 = __int_as_float(e0.y), w1 = __int_as_float(e1.y);
        float w2 = __int_as_float(e2.y), w3 = __int_as_float(e3.y);
        ACC8(azA, v0, w0);
        ACC8(azB, v1, w1);
        ACC8(azA, v2, w2);
        ACC8(azB, v3, w3);
    }
    for (; j < je; ++j) {
        int2 e0 = epack[j];
        H4 v0;
        v0.u = *reinterpret_cast<const uint4*>(rdB + (size_t)(unsigned)e0.x + cb);
        float w0 = __int_as_float(e0.y);
        ACC8(azA, v0, w0);
    }
#undef ACC8

    float az[8];
    #pragma unroll
    for (int i = 0; i < 8; ++i) az[i] = azA[i] + azB[i];

    size_t idx = (size_t)nidx * H_DIM + c;
    H4 sr; sr.u = *reinterpret_cast<const uint4*>(zsH + idx);
    float s[8];
    {
        float2 f0 = __half22float2(sr.h[0]), f1 = __half22float2(sr.h[1]);
        float2 f2 = __half22float2(sr.h[2]), f3 = __half22float2(sr.h[3]);
        s[0] = f0.x; s[1] = f0.y; s[2] = f1.x; s[3] = f1.y;
        s[4] = f2.x; s[5] = f2.y; s[6] = f3.x; s[7] = f3.y;
    }
    H4 xr; xr.u = *reinterpret_cast<const uint4*>(x0H + idx);
    float xv[8];
    {
        float2 f0 = __half22float2(xr.h[0]), f1 = __half22float2(xr.h[1]);
        float2 f2 = __half22float2(xr.h[2]), f3 = __half22float2(xr.h[3]);
        xv[0] = f0.x; xv[1] = f0.y; xv[2] = f1.x; xv[3] = f1.y;
        xv[4] = f2.x; xv[5] = f2.y; xv[6] = f3.x; xv[7] = f3.y;
    }
    float a = acoArr[nidx];

    float k[8];
    #pragma unroll
    for (int i = 0; i < 8; ++i) k[i] = fmaf(a, az[i] - s[i], xv[i]);

    float o[8];
    if constexpr (STAGE == 0) {
        H4 aw;
        aw.h[0] = __float22half2_rn(make_float2(k[0], k[1]));
        aw.h[1] = __float22half2_rn(make_float2(k[2], k[3]));
        aw.h[2] = __float22half2_rn(make_float2(k[4], k[5]));
        aw.h[3] = __float22half2_rn(make_float2(k[6], k[7]));
        *reinterpret_cast<uint4*>(accH + idx) = aw.u;
        #pragma unroll
        for (int i = 0; i < 8; ++i) o[i] = fmaf(cnext, k[i], s[i]);
    } else if constexpr (STAGE == 1 || STAGE == 2) {
        H4 ar; ar.u = *reinterpret_cast<const uint4*>(accH + idx);
        float av[8];
        {
            float2 f0 = __half22float2(ar.h[0]), f1 = __half22float2(ar.h[1]);
            float2 f2 = __half22float2(ar.h[2]), f3 = __half22float2(ar.h[3]);
            av[0] = f0.x; av[1] = f0.y; av[2] = f1.x; av[3] = f1.y;
            av[4] = f2.x; av[5] = f2.y; av[6] = f3.x; av[7] = f3.y;
        }
        #pragma unroll
        for (int i = 0; i < 8; ++i) av[i] = fmaf(2.f, k[i], av[i]);
        H4 aw;
        aw.h[0] = __float22half2_rn(make_float2(av[0], av[1]));
        aw.h[1] = __float22half2_rn(make_float2(av[2], av[3]));
        aw.h[2] = __float22half2_rn(make_float2(av[4], av[5]));
        aw.h[3] = __float22half2_rn(make_float2(av[6], av[7]));
        *reinterpret_cast<uint4*>(accH + idx) = aw.u;
        H4 br; br.u = *reinterpret_cast<const uint4*>(zH + idx);
        float bv[8];
        {
            float2 f0 = __half22float2(br.h[0]), f1 = __half22float2(br.h[1]);
            float2 f2 = __half22float2(br.h[2]), f3 = __half22float2(br.h[3]);
            bv[0] = f0.x; bv[1] = f0.y; bv[2] = f1.x; bv[3] = f1.y;
            bv[4] = f2.x; bv[5] = f2.y; bv[6] = f3.x; bv[7] = f3.y;
        }
        #pragma unroll
        for (int i = 0; i < 8; ++i) o[i] = fmaf(cnext, k[i], bv[i]);
    } else {
        H4 ar; ar.u = *reinterpret_cast<const uint4*>(accH + idx);
        float av[8];
        {
            float2 f0 = __half22float2(ar.h[0]), f1 = __half22float2(ar.h[1]);
            float2 f2 = __half22float2(ar.h[2]), f3 = __half22float2(ar.h[3]);
            av[0] = f0.x; av[1] = f0.y; av[2] = f1.x; av[3] = f1.y;
            av[4] = f2.x; av[5] = f2.y; av[6] = f3.x; av[7] = f3.y;
        }
        float4 zb0 = *reinterpret_cast<const float4*>(zbF + idx);
        float4 zb1 = *reinterpret_cast<const float4*>(zbF + idx + 4);
        float zb[8] = {zb0.x, zb0.y, zb0.z, zb0.w, zb1.x, zb1.y, zb1.z, zb1.w};
        #pragma unroll
        for (int i = 0; i < 8; ++i) o[i] = fmaf(cnext, av[i] + k[i], zb[i]);
        float4 oz0 = make_float4(o[0], o[1], o[2], o[3]);
        float4 oz1 = make_float4(o[4], o[5], o[6], o[7]);
        *reinterpret_cast<float4*>(outZ + idx)     = oz0;
        *reinterpret_cast<float4*>(outZ + idx + 4) = oz1;
    }
    H4 sv;
    sv.h[0] = __float22half2_rn(make_float2(o[0], o[1]));
    sv.h[1] = __float22half2_rn(make_float2(o[2], o[3]));
    sv.h[2] = __float22half2_rn(make_float2(o[4], o[5]));
    sv.h[3] = __float22half2_rn(make_float2(o[6], o[7]));
    *reinterpret_cast<uint4*>(outH + idx) = sv.u;
}

// ---------------- Decoder: sequential z read, permuted out write ----------
__global__ __launch_bounds__(256) void decoder_kernel(
    const float* __restrict__ z, const int* __restrict__ nodeOrd,
    const float* __restrict__ W2, const float* __restrict__ b2,
    float* __restrict__ out)
{
    __shared__ float zsm[4][H_DIM];
    int lane = threadIdx.x & 63;
    int w    = threadIdx.x >> 6;
    int node = blockIdx.x * 4 + w;
    int ld   = node >= N_NODES ? N_NODES - 1 : node;
    float zv = z[(size_t)ld * H_DIM + lane];
    zsm[w][lane] = zv > 0.f ? zv : 0.f;
    __syncthreads();
    if (node < N_NODES && lane < C_OUT) {
        float acc = b2[lane];
        #pragma unroll
        for (int k = 0; k < H_DIM; ++k)
            acc = fmaf(zsm[w][k], W2[k * C_OUT + lane], acc);
        out[(size_t)nodeOrd[node] * C_OUT + lane] = acc;
    }
}

extern "C" void kernel_launch(void* const* d_in, const int* in_sizes, int n_in,
                              void* d_out, int out_size, void* d_ws, size_t ws_size,
                              hipStream_t stream)
{
    const float* x     = (const float*)d_in[0];
    const float* ew    = (const float*)d_in[1];
    const float* m1w   = (const float*)d_in[2];
    const float* m1b   = (const float*)d_in[3];
    const float* alpha = (const float*)d_in[4];
    const float* m2w   = (const float*)d_in[5];
    const float* m2b   = (const float*)d_in[6];
    const int*   esrc  = (const int*)d_in[7];
    const int*   edst  = (const int*)d_in[8];
    float* out = (float*)d_out;

    char* ws = (char*)d_ws;
    size_t o = 0;
    auto alloc = [&](size_t bytes) -> void* {
        void* p = ws + o;
        o = (o + bytes + 255) & ~(size_t)255;
        return p;
    };
    float*  z      = (float*)alloc((size_t)N_NODES * H_DIM * 4);
    __half* x0H    = (__half*)alloc((size_t)N_NODES * H_DIM * 2);
    __half* zH     = (__half*)alloc((size_t)N_NODES * H_DIM * 2);
    __half* ztAH   = (__half*)alloc((size_t)N_NODES * H_DIM * 2);
    __half* ztBH   = (__half*)alloc((size_t)N_NODES * H_DIM * 2);
    __half* accH   = (__half*)alloc((size_t)N_NODES * H_DIM * 2);
    __half* bfrag  = (__half*)alloc((size_t)KTILES * 4 * 64 * 8 * 2);
    int*    counts = (int*)alloc((size_t)N_NODES * 4);
    int*    off    = (int*)alloc((size_t)(N_NODES + 1) * 4);
    int*    cursor = (int*)alloc((size_t)N_NODES * 4);
    int*    bsums  = (int*)alloc((size_t)NB_SCAN * 4);
    int*    bbases = (int*)alloc((size_t)NB_SCAN * 4);
    int*    bbc    = (int*)alloc((size_t)NB_SCAN * DBINS * 4);
    int*    bmat   = (int*)alloc((size_t)NB_SCAN * DBINS * 4);
    int*    nodeOrd= (int*)alloc((size_t)N_NODES * 4);
    int*    invOrd = (int*)alloc((size_t)N_NODES * 4);
    int*    jbArr  = (int*)alloc((size_t)N_NODES * 4);
    int*    jeArr  = (int*)alloc((size_t)N_NODES * 4);
    float*  acoArr = (float*)alloc((size_t)N_NODES * 4);
    int2*   epack  = (int2*)alloc((size_t)N_EDGES * 8);

    hipMemsetAsync(counts, 0, (size_t)N_NODES * 4, stream);
    hist_kernel<<<(N_EDGES + 255) / 256, 256, 0, stream>>>(esrc, counts);
    scanA_kernel<<<NB_SCAN, 256, 0, stream>>>(counts, bsums);
    scanB_kernel<<<1, 256, 0, stream>>>(bsums, bbases);
    scanC_kernel<<<NB_SCAN, 256, 0, stream>>>(counts, bbases, off, cursor);

    // contention-free degree sort + permutation tables
    blockHist_kernel<<<NB_SCAN, 256, 0, stream>>>(counts, bbc);
    degBase_kernel<<<1, 64, 0, stream>>>(bbc, bmat);
    degScatter_kernel<<<NB_SCAN, 256, 0, stream>>>(counts, bmat, nodeOrd);
    invOrd_kernel<<<NB_SCAN, 256, 0, stream>>>(nodeOrd, invOrd);
    permMeta_kernel<<<NB_SCAN, 256, 0, stream>>>(nodeOrd, off, alpha, jbArr, jeArr, acoArr);

    scatter_kernel<<<(N_EDGES + 255) / 256, 256, 0, stream>>>(esrc, edst, ew, invOrd, cursor, epack);

    bfrag_kernel<<<(KTILES * 4 * 64 + 255) / 256, 256, 0, stream>>>(m1w, bfrag);
    encoder_kernel<<<(N_NODES + 31) / 32, 256, 0, stream>>>(x, bfrag, m1b, invOrd, x0H, z, zH);

    const float dt = 1.0f / STEPS;
    int sgrid = (N_NODES + 31) / 32;
    for (int step = 0; step < STEPS; ++step) {
        stage_kernel<0><<<sgrid, 256, 0, stream>>>(jbArr, jeArr, acoArr, epack, zH,   zH, nullptr, x0H, accH, ztAH, nullptr, 0.5f * dt);
        stage_kernel<1><<<sgrid, 256, 0, stream>>>(jbArr, jeArr, acoArr, epack, ztAH, zH, nullptr, x0H, accH, ztBH, nullptr, 0.5f * dt);
        stage_kernel<2><<<sgrid, 256, 0, stream>>>(jbArr, jeArr, acoArr, epack, ztBH, zH, nullptr, x0H, accH, ztAH, nullptr, dt);
        stage_kernel<3><<<sgrid, 256, 0, stream>>>(jbArr, jeArr, acoArr, epack, ztAH, zH, z,       x0H, accH, zH,   z,       dt / 6.0f);
    }

    decoder_kernel<<<(N_NODES + 3) / 4, 256, 0, stream>>>(z, nodeOrd, m2w, m2b, out);
}

// Round 13
// 389.068 us; speedup vs baseline: 1.9210x; 1.0897x over previous
//
#include <hip/hip_runtime.h>
#include <hip/hip_fp16.h>

#define N_NODES 50000
#define N_EDGES 600000
#define F_IN    500
#define H_DIM   64
#define C_OUT   40
#define STEPS   4
#define NB_SCAN ((N_NODES + 255) / 256)   // 196
#define KTILES  16                        // 512 k padded, 32 per MFMA

using half8 = __attribute__((ext_vector_type(8))) _Float16;
using f32x4 = __attribute__((ext_vector_type(4))) float;

// ---------------- B-fragment precompute: W (500x64 f32) -> MFMA frags ------
__global__ __launch_bounds__(256) void bfrag_kernel(
    const float* __restrict__ W, __half* __restrict__ bfrag)
{
    int t = blockIdx.x * 256 + threadIdx.x;
    if (t >= KTILES * 4 * 64) return;
    int lane = t & 63;
    int c    = (t >> 6) & 3;
    int kt   = t >> 8;
    int col  = c * 16 + (lane & 15);
    int kb   = kt * 32 + (lane >> 4) * 8;
    union { uint4 u; __half h[8]; } v;
    #pragma unroll
    for (int j = 0; j < 8; ++j) {
        int k = kb + j;
        v.h[j] = (k < F_IN) ? __float2half(W[(size_t)k * H_DIM + col]) : __half(0.f);
    }
    *reinterpret_cast<uint4*>(bfrag + (size_t)t * 8) = v.u;
}

// ---------------- Encoder: MFMA GEMM, K split 4 ways, 16 rows/block -------
// 4 waves share one 16-row tile; wave w does k-tiles [4w, 4w+4). LDS reduce.
__global__ __launch_bounds__(256) void encoder_kernel(
    const float* __restrict__ x, const __half* __restrict__ bfrag,
    const float* __restrict__ b, __half* __restrict__ x0H,
    __half* __restrict__ zH)
{
    __shared__ f32x4 red[3][64][4];   // 12 KB

    int wave = threadIdx.x >> 6;
    int lane = threadIdx.x & 63;
    int rowl = lane & 15;
    int kg   = lane >> 4;              // 0..3
    int r0   = blockIdx.x * 16;

    int gr = r0 + rowl; if (gr >= N_NODES) gr = N_NODES - 1;
    const float* xrow = x + (size_t)gr * F_IN;
    const uint4* bf = reinterpret_cast<const uint4*>(bfrag);

    int ktb = wave * 4;

    float4 xv[8];
    #pragma unroll
    for (int ki = 0; ki < 4; ++ki) {
        int k0 = (ktb + ki) * 32 + kg * 8;
        xv[2 * ki]     = make_float4(0.f, 0.f, 0.f, 0.f);
        xv[2 * ki + 1] = make_float4(0.f, 0.f, 0.f, 0.f);
        if (k0 + 4 <= F_IN) xv[2 * ki]     = *reinterpret_cast<const float4*>(xrow + k0);
        if (k0 + 8 <= F_IN) xv[2 * ki + 1] = *reinterpret_cast<const float4*>(xrow + k0 + 4);
    }

    f32x4 acc[4];
    #pragma unroll
    for (int c = 0; c < 4; ++c) acc[c] = (f32x4){0.f, 0.f, 0.f, 0.f};

    #pragma unroll
    for (int ki = 0; ki < 4; ++ki) {
        int kt = ktb + ki;
        float4 xa = xv[2 * ki], xb = xv[2 * ki + 1];
        half8 a;
        a[0] = (_Float16)xa.x; a[1] = (_Float16)xa.y;
        a[2] = (_Float16)xa.z; a[3] = (_Float16)xa.w;
        a[4] = (_Float16)xb.x; a[5] = (_Float16)xb.y;
        a[6] = (_Float16)xb.z; a[7] = (_Float16)xb.w;
        #pragma unroll
        for (int c = 0; c < 4; ++c) {
            union { uint4 u; half8 h; } bv;
            bv.u = bf[(size_t)(kt * 4 + c) * 64 + lane];
            acc[c] = __builtin_amdgcn_mfma_f32_16x16x32_f16(a, bv.h, acc[c], 0, 0, 0);
        }
    }

    if (wave > 0) {
        #pragma unroll
        for (int c = 0; c < 4; ++c) red[wave - 1][lane][c] = acc[c];
    }
    __syncthreads();
    if (wave == 0) {
        #pragma unroll
        for (int w = 0; w < 3; ++w)
            #pragma unroll
            for (int c = 0; c < 4; ++c) {
                f32x4 r = red[w][lane][c];
                acc[c][0] += r[0]; acc[c][1] += r[1];
                acc[c][2] += r[2]; acc[c][3] += r[3];
            }
        #pragma unroll
        for (int c = 0; c < 4; ++c) {
            int col = c * 16 + rowl;
            float bias = b[col];
            #pragma unroll
            for (int r = 0; r < 4; ++r) {
                int grow = r0 + kg * 4 + r;
                if (grow < N_NODES) {
                    float v = acc[c][r] + bias;
                    size_t idx = (size_t)grow * H_DIM + col;
                    __half hv = __float2half(v);
                    zH[idx]  = hv;
                    x0H[idx] = hv;
                }
            }
        }
    }
}

// ---------------- CSR build ----------------
__global__ void hist_kernel(const int* __restrict__ src, int* __restrict__ counts)
{
    int e = blockIdx.x * 256 + threadIdx.x;
    if (e < N_EDGES) atomicAdd(&counts[src[e]], 1);
}

__global__ __launch_bounds__(256) void scanA_kernel(
    const int* __restrict__ counts, int* __restrict__ blockSums)
{
    __shared__ int red[256];
    int i = blockIdx.x * 256 + threadIdx.x;
    red[threadIdx.x] = (i < N_NODES) ? counts[i] : 0;
    __syncthreads();
    #pragma unroll
    for (int s = 128; s > 0; s >>= 1) {
        if (threadIdx.x < s) red[threadIdx.x] += red[threadIdx.x + s];
        __syncthreads();
    }
    if (threadIdx.x == 0) blockSums[blockIdx.x] = red[0];
}

__global__ __launch_bounds__(256) void scanB_kernel(
    const int* __restrict__ blockSums, int* __restrict__ blockBases)
{
    __shared__ int s[256];
    int tid = threadIdx.x;
    int v = (tid < NB_SCAN) ? blockSums[tid] : 0;
    s[tid] = v;
    __syncthreads();
    #pragma unroll
    for (int d = 1; d < 256; d <<= 1) {
        int t = (tid >= d) ? s[tid - d] : 0;
        __syncthreads();
        s[tid] += t;
        __syncthreads();
    }
    if (tid < NB_SCAN) blockBases[tid] = s[tid] - v;
}

__global__ __launch_bounds__(256) void scanC_kernel(
    const int* __restrict__ counts, const int* __restrict__ blockBases,
    int* __restrict__ off, int* __restrict__ cursor)
{
    __shared__ int s[256];
    int tid = threadIdx.x;
    int i = blockIdx.x * 256 + tid;
    int v = (i < N_NODES) ? counts[i] : 0;
    s[tid] = v;
    __syncthreads();
    #pragma unroll
    for (int d = 1; d < 256; d <<= 1) {
        int t = (tid >= d) ? s[tid - d] : 0;
        __syncthreads();
        s[tid] += t;
        __syncthreads();
    }
    if (i < N_NODES) {
        int excl = blockBases[blockIdx.x] + s[tid] - v;
        off[i] = excl;
        cursor[i] = excl;
        if (i == N_NODES - 1) off[N_NODES] = excl + v;
    }
}

// epack.x = dst * 128 (byte offset of the node's 128 B fp16 row)
__global__ void scatter_kernel(const int* __restrict__ src, const int* __restrict__ dst,
                               const float* __restrict__ w,
                               int* __restrict__ cursor, int2* __restrict__ epack)
{
    int e = blockIdx.x * 256 + threadIdx.x;
    if (e < N_EDGES) {
        int s = src[e];
        int p = atomicAdd(&cursor[s], 1);
        epack[p] = make_int2(dst[e] << 7, __float_as_int(w[e]));
    }
}

// ---------------- Fused RK4 stage: all-fp16 state, 8-lane groups -----------
// STAGE 0: gather zH; base = self; accH = k; out -> ztAH
// STAGE 1/2: gather zt*; base = zH; accH += 2k
// STAGE 3: gather ztAH; base = zH; out = base + cnext*(accH+k) -> zH (in place)
template<int STAGE>
__global__ __launch_bounds__(256) void stage_kernel(
    const int* __restrict__ off, const int2* __restrict__ epack,
    const __half* __restrict__ zsH, const __half* __restrict__ zH,
    const __half* __restrict__ x0H, const float* __restrict__ alpha,
    __half* __restrict__ accH, __half* __restrict__ outH, float cnext)
{
    int node = blockIdx.x * 32 + (threadIdx.x >> 3);
    if (node >= N_NODES) return;
    int cb = (threadIdx.x & 7) << 4;   // byte offset of this lane's 16B slice
    int c  = cb >> 1;                  // fp16 element offset

    int jb = off[node], je = off[node + 1];
    const char* rdB = reinterpret_cast<const char*>(zsH);

    union H4 { uint4 u; __half2 h[4]; };

    float azA[8], azB[8];
    #pragma unroll
    for (int i = 0; i < 8; ++i) { azA[i] = 0.f; azB[i] = 0.f; }

#define ACC8(dst, V, W)                                                    \
    {                                                                      \
        float2 f0 = __half22float2((V).h[0]);                              \
        float2 f1 = __half22float2((V).h[1]);                              \
        float2 f2 = __half22float2((V).h[2]);                              \
        float2 f3 = __half22float2((V).h[3]);                              \
        dst[0] = fmaf(W, f0.x, dst[0]); dst[1] = fmaf(W, f0.y, dst[1]);    \
        dst[2] = fmaf(W, f1.x, dst[2]); dst[3] = fmaf(W, f1.y, dst[3]);    \
        dst[4] = fmaf(W, f2.x, dst[4]); dst[5] = fmaf(W, f2.y, dst[5]);    \
        dst[6] = fmaf(W, f3.x, dst[6]); dst[7] = fmaf(W, f3.y, dst[7]);    \
    }

    int j = jb;
    for (; j + 3 < je; j += 4) {
        int2 e0 = epack[j];
        int2 e1 = epack[j + 1];
        int2 e2 = epack[j + 2];
        int2 e3 = epack[j + 3];
        H4 v0, v1, v2, v3;
        v0.u = *reinterpret_cast<const uint4*>(rdB + (size_t)(unsigned)e0.x + cb);
        v1.u = *reinterpret_cast<const uint4*>(rdB + (size_t)(unsigned)e1.x + cb);
        v2.u = *reinterpret_cast<const uint4*>(rdB + (size_t)(unsigned)e2.x + cb);
        v3.u = *reinterpret_cast<const uint4*>(rdB + (size_t)(unsigned)e3.x + cb);
        float w0 = __int_as_float(e0.y), w1 = __int_as_float(e1.y);
        float w2 = __int_as_float(e2.y), w3 = __int_as_float(e3.y);
        ACC8(azA, v0, w0);
        ACC8(azB, v1, w1);
        ACC8(azA, v2, w2);
        ACC8(azB, v3, w3);
    }
    for (; j < je; ++j) {
        int2 e0 = epack[j];
        H4 v0;
        v0.u = *reinterpret_cast<const uint4*>(rdB + (size_t)(unsigned)e0.x + cb);
        float w0 = __int_as_float(e0.y);
        ACC8(azA, v0, w0);
    }
#undef ACC8

    float az[8];
    #pragma unroll
    for (int i = 0; i < 8; ++i) az[i] = azA[i] + azB[i];

    size_t idx = (size_t)node * H_DIM + c;
    H4 sr; sr.u = *reinterpret_cast<const uint4*>(zsH + idx);
    float s[8];
    {
        float2 f0 = __half22float2(sr.h[0]), f1 = __half22float2(sr.h[1]);
        float2 f2 = __half22float2(sr.h[2]), f3 = __half22float2(sr.h[3]);
        s[0] = f0.x; s[1] = f0.y; s[2] = f1.x; s[3] = f1.y;
        s[4] = f2.x; s[5] = f2.y; s[6] = f3.x; s[7] = f3.y;
    }
    H4 xr; xr.u = *reinterpret_cast<const uint4*>(x0H + idx);
    float xv[8];
    {
        float2 f0 = __half22float2(xr.h[0]), f1 = __half22float2(xr.h[1]);
        float2 f2 = __half22float2(xr.h[2]), f3 = __half22float2(xr.h[3]);
        xv[0] = f0.x; xv[1] = f0.y; xv[2] = f1.x; xv[3] = f1.y;
        xv[4] = f2.x; xv[5] = f2.y; xv[6] = f3.x; xv[7] = f3.y;
    }
    float a = 0.5f / (1.f + __expf(-alpha[node]));

    float k[8];
    #pragma unroll
    for (int i = 0; i < 8; ++i) k[i] = fmaf(a, az[i] - s[i], xv[i]);

    float o[8];
    if constexpr (STAGE == 0) {
        H4 aw;
        aw.h[0] = __float22half2_rn(make_float2(k[0], k[1]));
        aw.h[1] = __float22half2_rn(make_float2(k[2], k[3]));
        aw.h[2] = __float22half2_rn(make_float2(k[4], k[5]));
        aw.h[3] = __float22half2_rn(make_float2(k[6], k[7]));
        *reinterpret_cast<uint4*>(accH + idx) = aw.u;
        #pragma unroll
        for (int i = 0; i < 8; ++i) o[i] = fmaf(cnext, k[i], s[i]);
    } else if constexpr (STAGE == 1 || STAGE == 2) {
        H4 ar; ar.u = *reinterpret_cast<const uint4*>(accH + idx);
        float av[8];
        {
            float2 f0 = __half22float2(ar.h[0]), f1 = __half22float2(ar.h[1]);
            float2 f2 = __half22float2(ar.h[2]), f3 = __half22float2(ar.h[3]);
            av[0] = f0.x; av[1] = f0.y; av[2] = f1.x; av[3] = f1.y;
            av[4] = f2.x; av[5] = f2.y; av[6] = f3.x; av[7] = f3.y;
        }
        #pragma unroll
        for (int i = 0; i < 8; ++i) av[i] = fmaf(2.f, k[i], av[i]);
        H4 aw;
        aw.h[0] = __float22half2_rn(make_float2(av[0], av[1]));
        aw.h[1] = __float22half2_rn(make_float2(av[2], av[3]));
        aw.h[2] = __float22half2_rn(make_float2(av[4], av[5]));
        aw.h[3] = __float22half2_rn(make_float2(av[6], av[7]));
        *reinterpret_cast<uint4*>(accH + idx) = aw.u;
        H4 br; br.u = *reinterpret_cast<const uint4*>(zH + idx);
        float bv[8];
        {
            float2 f0 = __half22float2(br.h[0]), f1 = __half22float2(br.h[1]);
            float2 f2 = __half22float2(br.h[2]), f3 = __half22float2(br.h[3]);
            bv[0] = f0.x; bv[1] = f0.y; bv[2] = f1.x; bv[3] = f1.y;
            bv[4] = f2.x; bv[5] = f2.y; bv[6] = f3.x; bv[7] = f3.y;
        }
        #pragma unroll
        for (int i = 0; i < 8; ++i) o[i] = fmaf(cnext, k[i], bv[i]);
    } else {
        H4 ar; ar.u = *reinterpret_cast<const uint4*>(accH + idx);
        float av[8];
        {
            float2 f0 = __half22float2(ar.h[0]), f1 = __half22float2(ar.h[1]);
            float2 f2 = __half22float2(ar.h[2]), f3 = __half22float2(ar.h[3]);
            av[0] = f0.x; av[1] = f0.y; av[2] = f1.x; av[3] = f1.y;
            av[4] = f2.x; av[5] = f2.y; av[6] = f3.x; av[7] = f3.y;
        }
        H4 br; br.u = *reinterpret_cast<const uint4*>(zH + idx);
        float bv[8];
        {
            float2 f0 = __half22float2(br.h[0]), f1 = __half22float2(br.h[1]);
            float2 f2 = __half22float2(br.h[2]), f3 = __half22float2(br.h[3]);
            bv[0] = f0.x; bv[1] = f0.y; bv[2] = f1.x; bv[3] = f1.y;
            bv[4] = f2.x; bv[5] = f2.y; bv[6] = f3.x; bv[7] = f3.y;
        }
        #pragma unroll
        for (int i = 0; i < 8; ++i) o[i] = fmaf(cnext, av[i] + k[i], bv[i]);
    }
    H4 sv;
    sv.h[0] = __float22half2_rn(make_float2(o[0], o[1]));
    sv.h[1] = __float22half2_rn(make_float2(o[2], o[3]));
    sv.h[2] = __float22half2_rn(make_float2(o[4], o[5]));
    sv.h[3] = __float22half2_rn(make_float2(o[6], o[7]));
    *reinterpret_cast<uint4*>(outH + idx) = sv.u;
}

// ---------------- Decoder: out = relu(z) @ m2_w + m2_b (fp16 z) -----------
__global__ __launch_bounds__(256) void decoder_kernel(
    const __half* __restrict__ zH, const float* __restrict__ W2,
    const float* __restrict__ b2, float* __restrict__ out)
{
    __shared__ float zsm[4][H_DIM];
    int lane = threadIdx.x & 63;
    int w    = threadIdx.x >> 6;
    int node = blockIdx.x * 4 + w;
    int ld   = node >= N_NODES ? N_NODES - 1 : node;
    float zv = __half2float(zH[(size_t)ld * H_DIM + lane]);
    zsm[w][lane] = zv > 0.f ? zv : 0.f;
    __syncthreads();
    if (node < N_NODES && lane < C_OUT) {
        float acc = b2[lane];
        #pragma unroll
        for (int k = 0; k < H_DIM; ++k)
            acc = fmaf(zsm[w][k], W2[k * C_OUT + lane], acc);
        out[(size_t)node * C_OUT + lane] = acc;
    }
}

extern "C" void kernel_launch(void* const* d_in, const int* in_sizes, int n_in,
                              void* d_out, int out_size, void* d_ws, size_t ws_size,
                              hipStream_t stream)
{
    const float* x     = (const float*)d_in[0];
    const float* ew    = (const float*)d_in[1];
    const float* m1w   = (const float*)d_in[2];
    const float* m1b   = (const float*)d_in[3];
    const float* alpha = (const float*)d_in[4];
    const float* m2w   = (const float*)d_in[5];
    const float* m2b   = (const float*)d_in[6];
    const int*   esrc  = (const int*)d_in[7];
    const int*   edst  = (const int*)d_in[8];
    float* out = (float*)d_out;

    char* ws = (char*)d_ws;
    size_t o = 0;
    auto alloc = [&](size_t bytes) -> void* {
        void* p = ws + o;
        o = (o + bytes + 255) & ~(size_t)255;
        return p;
    };
    __half* x0H    = (__half*)alloc((size_t)N_NODES * H_DIM * 2);
    __half* zH     = (__half*)alloc((size_t)N_NODES * H_DIM * 2);
    __half* ztAH   = (__half*)alloc((size_t)N_NODES * H_DIM * 2);
    __half* ztBH   = (__half*)alloc((size_t)N_NODES * H_DIM * 2);
    __half* accH   = (__half*)alloc((size_t)N_NODES * H_DIM * 2);
    __half* bfrag  = (__half*)alloc((size_t)KTILES * 4 * 64 * 8 * 2);
    int*    counts = (int*)alloc((size_t)N_NODES * 4);
    int*    off    = (int*)alloc((size_t)(N_NODES + 1) * 4);
    int*    cursor = (int*)alloc((size_t)N_NODES * 4);
    int*    bsums  = (int*)alloc((size_t)NB_SCAN * 4);
    int*    bbases = (int*)alloc((size_t)NB_SCAN * 4);
    int2*   epack  = (int2*)alloc((size_t)N_EDGES * 8);

    hipMemsetAsync(counts, 0, (size_t)N_NODES * 4, stream);
    hist_kernel<<<(N_EDGES + 255) / 256, 256, 0, stream>>>(esrc, counts);
    scanA_kernel<<<NB_SCAN, 256, 0, stream>>>(counts, bsums);
    scanB_kernel<<<1, 256, 0, stream>>>(bsums, bbases);
    scanC_kernel<<<NB_SCAN, 256, 0, stream>>>(counts, bbases, off, cursor);
    scatter_kernel<<<(N_EDGES + 255) / 256, 256, 0, stream>>>(esrc, edst, ew, cursor, epack);

    bfrag_kernel<<<(KTILES * 4 * 64 + 255) / 256, 256, 0, stream>>>(m1w, bfrag);
    encoder_kernel<<<(N_NODES + 15) / 16, 256, 0, stream>>>(x, bfrag, m1b, x0H, zH);

    const float dt = 1.0f / STEPS;
    int sgrid = (N_NODES + 31) / 32;
    for (int step = 0; step < STEPS; ++step) {
        stage_kernel<0><<<sgrid, 256, 0, stream>>>(off, epack, zH,   zH, x0H, alpha, accH, ztAH, 0.5f * dt);
        stage_kernel<1><<<sgrid, 256, 0, stream>>>(off, epack, ztAH, zH, x0H, alpha, accH, ztBH, 0.5f * dt);
        stage_kernel<2><<<sgrid, 256, 0, stream>>>(off, epack, ztBH, zH, x0H, alpha, accH, ztAH, dt);
        stage_kernel<3><<<sgrid, 256, 0, stream>>>(off, epack, ztAH, zH, x0H, alpha, accH, zH,   dt / 6.0f);
    }

    decoder_kernel<<<(N_NODES + 3) / 4, 256, 0, stream>>>(zH, m2w, m2b, out);
}

// Round 15
// 362.548 us; speedup vs baseline: 2.0615x; 1.0731x over previous
//
#include <hip/hip_runtime.h>
#include <hip/hip_fp16.h>

#define N_NODES 50000
#define N_EDGES 600000
#define F_IN    500
#define H_DIM   64
#define C_OUT   40
#define STEPS   4
#define NB_SCAN ((N_NODES + 255) / 256)   // 196
#define KTILES  16                        // 512 k padded, 32 per MFMA
#define XS_COLS 516                       // 16B-aligned rows, 2-way banks (free)

using half8 = __attribute__((ext_vector_type(8))) _Float16;
using f32x4 = __attribute__((ext_vector_type(4))) float;

// ---------------- B-fragment precompute: W (500x64 f32) -> MFMA frags ------
__global__ __launch_bounds__(256) void bfrag_kernel(
    const float* __restrict__ W, __half* __restrict__ bfrag)
{
    int t = blockIdx.x * 256 + threadIdx.x;
    if (t >= KTILES * 4 * 64) return;
    int lane = t & 63;
    int c    = (t >> 6) & 3;
    int kt   = t >> 8;
    int col  = c * 16 + (lane & 15);
    int kb   = kt * 32 + (lane >> 4) * 8;
    union { uint4 u; __half h[8]; } v;
    #pragma unroll
    for (int j = 0; j < 8; ++j) {
        int k = kb + j;
        v.h[j] = (k < F_IN) ? __float2half(W[(size_t)k * H_DIM + col]) : __half(0.f);
    }
    *reinterpret_cast<uint4*>(bfrag + (size_t)t * 8) = v.u;
}

// ---------------- Encoder: full-row streamed x -> LDS -> MFMA --------------
// 16 rows/block. Wave w stages rows 4w..4w+3 with LINEAR sweeps (2000 B
// contiguous per row -> DRAM-page friendly). MFMA K-split 4 ways + LDS
// reduce. Epilogue transposes via LDS -> vectorized 2x16 B fp16 stores.
__global__ __launch_bounds__(256) void encoder_kernel(
    const float* __restrict__ x, const __half* __restrict__ bfrag,
    const float* __restrict__ b, __half* __restrict__ x0H,
    __half* __restrict__ zH)
{
    __shared__ __align__(16) float xs[16][XS_COLS];   // 33 KB
    __shared__ f32x4 red[3][64][4];                   // 12 KB
    __shared__ float outs[16][68];                    // 4.4 KB

    int t    = threadIdx.x;
    int wave = t >> 6;
    int lane = t & 63;
    int r0   = blockIdx.x * 16;

    // ---- stage: wave w reads rows 4w..4w+3, linear 16B chunks ----
    #pragma unroll
    for (int i = 0; i < 8; ++i) {
        int c = i * 64 + lane;            // 0..499 chunk index within 4 rows
        if (c < 500) {
            int row = c / 125;            // 0..3
            int cc  = c - row * 125;      // 0..124 (16B chunks)
            int grow = r0 + wave * 4 + row;
            if (grow >= N_NODES) grow = N_NODES - 1;
            float4 v = *reinterpret_cast<const float4*>(x + (size_t)grow * F_IN + cc * 4);
            *reinterpret_cast<float4*>(&xs[wave * 4 + row][cc * 4]) = v;
        }
    }
    // zero-pad cols 500..515
    xs[t >> 4][500 + (t & 15)] = 0.f;
    __syncthreads();

    int rowl = lane & 15;
    int kg   = lane >> 4;                 // 0..3
    const uint4* bf = reinterpret_cast<const uint4*>(bfrag);

    f32x4 acc[4];
    #pragma unroll
    for (int c = 0; c < 4; ++c) acc[c] = (f32x4){0.f, 0.f, 0.f, 0.f};

    int ktb = wave * 4;
    #pragma unroll
    for (int ki = 0; ki < 4; ++ki) {
        int kt = ktb + ki;
        int k0 = kt * 32 + kg * 8;
        float4 xa = *reinterpret_cast<const float4*>(&xs[rowl][k0]);
        float4 xb = *reinterpret_cast<const float4*>(&xs[rowl][k0 + 4]);
        half8 a;
        a[0] = (_Float16)xa.x; a[1] = (_Float16)xa.y;
        a[2] = (_Float16)xa.z; a[3] = (_Float16)xa.w;
        a[4] = (_Float16)xb.x; a[5] = (_Float16)xb.y;
        a[6] = (_Float16)xb.z; a[7] = (_Float16)xb.w;
        #pragma unroll
        for (int c = 0; c < 4; ++c) {
            union { uint4 u; half8 h; } bv;
            bv.u = bf[(size_t)(kt * 4 + c) * 64 + lane];
            acc[c] = __builtin_amdgcn_mfma_f32_16x16x32_f16(a, bv.h, acc[c], 0, 0, 0);
        }
    }

    if (wave > 0) {
        #pragma unroll
        for (int c = 0; c < 4; ++c) red[wave - 1][lane][c] = acc[c];
    }
    __syncthreads();
    if (wave == 0) {
        #pragma unroll
        for (int w = 0; w < 3; ++w)
            #pragma unroll
            for (int c = 0; c < 4; ++c) {
                f32x4 r = red[w][lane][c];
                acc[c][0] += r[0]; acc[c][1] += r[1];
                acc[c][2] += r[2]; acc[c][3] += r[3];
            }
        // transpose to row-major via LDS (+bias)
        #pragma unroll
        for (int c = 0; c < 4; ++c) {
            int col = c * 16 + rowl;
            float bias = b[col];
            #pragma unroll
            for (int r = 0; r < 4; ++r)
                outs[kg * 4 + r][col] = acc[c][r] + bias;
        }
        // same-wave LDS RAW is in-order; 2x16 B vector fp16 stores per lane
        int orow = lane >> 2;             // 0..15
        int ocb  = (lane & 3) * 16;       // 0,16,32,48
        int grow = r0 + orow;
        if (grow < N_NODES) {
            union { uint4 u[2]; __half h[16]; } pk;
            #pragma unroll
            for (int i = 0; i < 16; ++i) pk.h[i] = __float2half(outs[orow][ocb + i]);
            size_t idx = (size_t)grow * H_DIM + ocb;
            *reinterpret_cast<uint4*>(zH  + idx)     = pk.u[0];
            *reinterpret_cast<uint4*>(zH  + idx + 8) = pk.u[1];
            *reinterpret_cast<uint4*>(x0H + idx)     = pk.u[0];
            *reinterpret_cast<uint4*>(x0H + idx + 8) = pk.u[1];
        }
    }
}

// ---------------- CSR build ----------------
__global__ void hist_kernel(const int* __restrict__ src, int* __restrict__ counts)
{
    int e = blockIdx.x * 256 + threadIdx.x;
    if (e < N_EDGES) atomicAdd(&counts[src[e]], 1);
}

__global__ __launch_bounds__(256) void scanA_kernel(
    const int* __restrict__ counts, int* __restrict__ blockSums)
{
    __shared__ int red[256];
    int i = blockIdx.x * 256 + threadIdx.x;
    red[threadIdx.x] = (i < N_NODES) ? counts[i] : 0;
    __syncthreads();
    #pragma unroll
    for (int s = 128; s > 0; s >>= 1) {
        if (threadIdx.x < s) red[threadIdx.x] += red[threadIdx.x + s];
        __syncthreads();
    }
    if (threadIdx.x == 0) blockSums[blockIdx.x] = red[0];
}

__global__ __launch_bounds__(256) void scanB_kernel(
    const int* __restrict__ blockSums, int* __restrict__ blockBases)
{
    __shared__ int s[256];
    int tid = threadIdx.x;
    int v = (tid < NB_SCAN) ? blockSums[tid] : 0;
    s[tid] = v;
    __syncthreads();
    #pragma unroll
    for (int d = 1; d < 256; d <<= 1) {
        int t = (tid >= d) ? s[tid - d] : 0;
        __syncthreads();
        s[tid] += t;
        __syncthreads();
    }
    if (tid < NB_SCAN) blockBases[tid] = s[tid] - v;
}

__global__ __launch_bounds__(256) void scanC_kernel(
    const int* __restrict__ counts, const int* __restrict__ blockBases,
    int* __restrict__ off, int* __restrict__ cursor)
{
    __shared__ int s[256];
    int tid = threadIdx.x;
    int i = blockIdx.x * 256 + tid;
    int v = (i < N_NODES) ? counts[i] : 0;
    s[tid] = v;
    __syncthreads();
    #pragma unroll
    for (int d = 1; d < 256; d <<= 1) {
        int t = (tid >= d) ? s[tid - d] : 0;
        __syncthreads();
        s[tid] += t;
        __syncthreads();
    }
    if (i < N_NODES) {
        int excl = blockBases[blockIdx.x] + s[tid] - v;
        off[i] = excl;
        cursor[i] = excl;
        if (i == N_NODES - 1) off[N_NODES] = excl + v;
    }
}

// epack = dst (16 bits) | fp16 weight (16 bits)  -> 4 B/edge
__global__ void scatter_kernel(const int* __restrict__ src, const int* __restrict__ dst,
                               const float* __restrict__ w,
                               int* __restrict__ cursor, unsigned* __restrict__ epack)
{
    int e = blockIdx.x * 256 + threadIdx.x;
    if (e < N_EDGES) {
        int s = src[e];
        int p = atomicAdd(&cursor[s], 1);
        unsigned wh = (unsigned)__half_as_ushort(__float2half(w[e]));
        epack[p] = (unsigned)dst[e] | (wh << 16);
    }
}

// ---------------- Fused RK4 stage: all-fp16 state, 8-lane groups -----------
// STAGE 0: gather zH; base = self; accH = k; out -> ztAH
// STAGE 1/2: gather zt*; base = zH; accH += 2k
// STAGE 3: gather ztAH; base = zH; out = base + cnext*(accH+k) -> zH
template<int STAGE>
__global__ __launch_bounds__(256) void stage_kernel(
    const int* __restrict__ off, const unsigned* __restrict__ epack,
    const __half* __restrict__ zsH, const __half* __restrict__ zH,
    const __half* __restrict__ x0H, const float* __restrict__ alpha,
    __half* __restrict__ accH, __half* __restrict__ outH, float cnext)
{
    int node = blockIdx.x * 32 + (threadIdx.x >> 3);
    if (node >= N_NODES) return;
    int cb = (threadIdx.x & 7) << 4;   // byte offset of this lane's 16B slice
    int c  = cb >> 1;                  // fp16 element offset

    int jb = off[node], je = off[node + 1];
    const char* rdB = reinterpret_cast<const char*>(zsH);

    union H4 { uint4 u; __half2 h[4]; };
    union HW { unsigned short us; __half h; };

    float azA[8], azB[8];
    #pragma unroll
    for (int i = 0; i < 8; ++i) { azA[i] = 0.f; azB[i] = 0.f; }

#define WOF(E)  ((size_t)((E) & 0xFFFFu) << 7)
#define WGT(E)  ({ HW hw_; hw_.us = (unsigned short)((E) >> 16); __half2float(hw_.h); })
#define ACC8(dst, V, W)                                                    \
    {                                                                      \
        float2 f0 = __half22float2((V).h[0]);                              \
        float2 f1 = __half22float2((V).h[1]);                              \
        float2 f2 = __half22float2((V).h[2]);                              \
        float2 f3 = __half22float2((V).h[3]);                              \
        dst[0] = fmaf(W, f0.x, dst[0]); dst[1] = fmaf(W, f0.y, dst[1]);    \
        dst[2] = fmaf(W, f1.x, dst[2]); dst[3] = fmaf(W, f1.y, dst[3]);    \
        dst[4] = fmaf(W, f2.x, dst[4]); dst[5] = fmaf(W, f2.y, dst[5]);    \
        dst[6] = fmaf(W, f3.x, dst[6]); dst[7] = fmaf(W, f3.y, dst[7]);    \
    }

    int j = jb;
    for (; j + 3 < je; j += 4) {
        unsigned e0 = epack[j];
        unsigned e1 = epack[j + 1];
        unsigned e2 = epack[j + 2];
        unsigned e3 = epack[j + 3];
        H4 v0, v1, v2, v3;
        v0.u = *reinterpret_cast<const uint4*>(rdB + WOF(e0) + cb);
        v1.u = *reinterpret_cast<const uint4*>(rdB + WOF(e1) + cb);
        v2.u = *reinterpret_cast<const uint4*>(rdB + WOF(e2) + cb);
        v3.u = *reinterpret_cast<const uint4*>(rdB + WOF(e3) + cb);
        float w0 = WGT(e0), w1 = WGT(e1), w2 = WGT(e2), w3 = WGT(e3);
        ACC8(azA, v0, w0);
        ACC8(azB, v1, w1);
        ACC8(azA, v2, w2);
        ACC8(azB, v3, w3);
    }
    for (; j < je; ++j) {
        unsigned e0 = epack[j];
        H4 v0;
        v0.u = *reinterpret_cast<const uint4*>(rdB + WOF(e0) + cb);
        float w0 = WGT(e0);
        ACC8(azA, v0, w0);
    }
#undef ACC8
#undef WOF
#undef WGT

    float az[8];
    #pragma unroll
    for (int i = 0; i < 8; ++i) az[i] = azA[i] + azB[i];

    size_t idx = (size_t)node * H_DIM + c;
    H4 sr; sr.u = *reinterpret_cast<const uint4*>(zsH + idx);
    float s[8];
    {
        float2 f0 = __half22float2(sr.h[0]), f1 = __half22float2(sr.h[1]);
        float2 f2 = __half22float2(sr.h[2]), f3 = __half22float2(sr.h[3]);
        s[0] = f0.x; s[1] = f0.y; s[2] = f1.x; s[3] = f1.y;
        s[4] = f2.x; s[5] = f2.y; s[6] = f3.x; s[7] = f3.y;
    }
    H4 xr; xr.u = *reinterpret_cast<const uint4*>(x0H + idx);
    float xv[8];
    {
        float2 f0 = __half22float2(xr.h[0]), f1 = __half22float2(xr.h[1]);
        float2 f2 = __half22float2(xr.h[2]), f3 = __half22float2(xr.h[3]);
        xv[0] = f0.x; xv[1] = f0.y; xv[2] = f1.x; xv[3] = f1.y;
        xv[4] = f2.x; xv[5] = f2.y; xv[6] = f3.x; xv[7] = f3.y;
    }
    float a = 0.5f / (1.f + __expf(-alpha[node]));

    float k[8];
    #pragma unroll
    for (int i = 0; i < 8; ++i) k[i] = fmaf(a, az[i] - s[i], xv[i]);

    float o[8];
    if constexpr (STAGE == 0) {
        H4 aw;
        aw.h[0] = __float22half2_rn(make_float2(k[0], k[1]));
        aw.h[1] = __float22half2_rn(make_float2(k[2], k[3]));
        aw.h[2] = __float22half2_rn(make_float2(k[4], k[5]));
        aw.h[3] = __float22half2_rn(make_float2(k[6], k[7]));
        *reinterpret_cast<uint4*>(accH + idx) = aw.u;
        #pragma unroll
        for (int i = 0; i < 8; ++i) o[i] = fmaf(cnext, k[i], s[i]);
    } else if constexpr (STAGE == 1 || STAGE == 2) {
        H4 ar; ar.u = *reinterpret_cast<const uint4*>(accH + idx);
        float av[8];
        {
            float2 f0 = __half22float2(ar.h[0]), f1 = __half22float2(ar.h[1]);
            float2 f2 = __half22float2(ar.h[2]), f3 = __half22float2(ar.h[3]);
            av[0] = f0.x; av[1] = f0.y; av[2] = f1.x; av[3] = f1.y;
            av[4] = f2.x; av[5] = f2.y; av[6] = f3.x; av[7] = f3.y;
        }
        #pragma unroll
        for (int i = 0; i < 8; ++i) av[i] = fmaf(2.f, k[i], av[i]);
        H4 aw;
        aw.h[0] = __float22half2_rn(make_float2(av[0], av[1]));
        aw.h[1] = __float22half2_rn(make_float2(av[2], av[3]));
        aw.h[2] = __float22half2_rn(make_float2(av[4], av[5]));
        aw.h[3] = __float22half2_rn(make_float2(av[6], av[7]));
        *reinterpret_cast<uint4*>(accH + idx) = aw.u;
        H4 br; br.u = *reinterpret_cast<const uint4*>(zH + idx);
        float bv[8];
        {
            float2 f0 = __half22float2(br.h[0]), f1 = __half22float2(br.h[1]);
            float2 f2 = __half22float2(br.h[2]), f3 = __half22float2(br.h[3]);
            bv[0] = f0.x; bv[1] = f0.y; bv[2] = f1.x; bv[3] = f1.y;
            bv[4] = f2.x; bv[5] = f2.y; bv[6] = f3.x; bv[7] = f3.y;
        }
        #pragma unroll
        for (int i = 0; i < 8; ++i) o[i] = fmaf(cnext, k[i], bv[i]);
    } else {
        H4 ar; ar.u = *reinterpret_cast<const uint4*>(accH + idx);
        float av[8];
        {
            float2 f0 = __half22float2(ar.h[0]), f1 = __half22float2(ar.h[1]);
            float2 f2 = __half22float2(ar.h[2]), f3 = __half22float2(ar.h[3]);
            av[0] = f0.x; av[1] = f0.y; av[2] = f1.x; av[3] = f1.y;
            av[4] = f2.x; av[5] = f2.y; av[6] = f3.x; av[7] = f3.y;
        }
        H4 br; br.u = *reinterpret_cast<const uint4*>(zH + idx);
        float bv[8];
        {
            float2 f0 = __half22float2(br.h[0]), f1 = __half22float2(br.h[1]);
            float2 f2 = __half22float2(br.h[2]), f3 = __half22float2(br.h[3]);
            bv[0] = f0.x; bv[1] = f0.y; bv[2] = f1.x; bv[3] = f1.y;
            bv[4] = f2.x; bv[5] = f2.y; bv[6] = f3.x; bv[7] = f3.y;
        }
        #pragma unroll
        for (int i = 0; i < 8; ++i) o[i] = fmaf(cnext, av[i] + k[i], bv[i]);
    }
    H4 sv;
    sv.h[0] = __float22half2_rn(make_float2(o[0], o[1]));
    sv.h[1] = __float22half2_rn(make_float2(o[2], o[3]));
    sv.h[2] = __float22half2_rn(make_float2(o[4], o[5]));
    sv.h[3] = __float22half2_rn(make_float2(o[6], o[7]));
    *reinterpret_cast<uint4*>(outH + idx) = sv.u;
}

// ---------------- Decoder: out = relu(z) @ m2_w + m2_b (fp16 z) -----------
__global__ __launch_bounds__(256) void decoder_kernel(
    const __half* __restrict__ zH, const float* __restrict__ W2,
    const float* __restrict__ b2, float* __restrict__ out)
{
    __shared__ float zsm[4][H_DIM];
    int lane = threadIdx.x & 63;
    int w    = threadIdx.x >> 6;
    int node = blockIdx.x * 4 + w;
    int ld   = node >= N_NODES ? N_NODES - 1 : node;
    float zv = __half2float(zH[(size_t)ld * H_DIM + lane]);
    zsm[w][lane] = zv > 0.f ? zv : 0.f;
    __syncthreads();
    if (node < N_NODES && lane < C_OUT) {
        float acc = b2[lane];
        #pragma unroll
        for (int k = 0; k < H_DIM; ++k)
            acc = fmaf(zsm[w][k], W2[k * C_OUT + lane], acc);
        out[(size_t)node * C_OUT + lane] = acc;
    }
}

extern "C" void kernel_launch(void* const* d_in, const int* in_sizes, int n_in,
                              void* d_out, int out_size, void* d_ws, size_t ws_size,
                              hipStream_t stream)
{
    const float* x     = (const float*)d_in[0];
    const float* ew    = (const float*)d_in[1];
    const float* m1w   = (const float*)d_in[2];
    const float* m1b   = (const float*)d_in[3];
    const float* alpha = (const float*)d_in[4];
    const float* m2w   = (const float*)d_in[5];
    const float* m2b   = (const float*)d_in[6];
    const int*   esrc  = (const int*)d_in[7];
    const int*   edst  = (const int*)d_in[8];
    float* out = (float*)d_out;

    char* ws = (char*)d_ws;
    size_t o = 0;
    auto alloc = [&](size_t bytes) -> void* {
        void* p = ws + o;
        o = (o + bytes + 255) & ~(size_t)255;
        return p;
    };
    __half*   x0H    = (__half*)alloc((size_t)N_NODES * H_DIM * 2);
    __half*   zH     = (__half*)alloc((size_t)N_NODES * H_DIM * 2);
    __half*   ztAH   = (__half*)alloc((size_t)N_NODES * H_DIM * 2);
    __half*   ztBH   = (__half*)alloc((size_t)N_NODES * H_DIM * 2);
    __half*   accH   = (__half*)alloc((size_t)N_NODES * H_DIM * 2);
    __half*   bfrag  = (__half*)alloc((size_t)KTILES * 4 * 64 * 8 * 2);
    int*      counts = (int*)alloc((size_t)N_NODES * 4);
    int*      off    = (int*)alloc((size_t)(N_NODES + 1) * 4);
    int*      cursor = (int*)alloc((size_t)N_NODES * 4);
    int*      bsums  = (int*)alloc((size_t)NB_SCAN * 4);
    int*      bbases = (int*)alloc((size_t)NB_SCAN * 4);
    unsigned* epack  = (unsigned*)alloc((size_t)N_EDGES * 4);

    hipMemsetAsync(counts, 0, (size_t)N_NODES * 4, stream);
    hist_kernel<<<(N_EDGES + 255) / 256, 256, 0, stream>>>(esrc, counts);
    scanA_kernel<<<NB_SCAN, 256, 0, stream>>>(counts, bsums);
    scanB_kernel<<<1, 256, 0, stream>>>(bsums, bbases);
    scanC_kernel<<<NB_SCAN, 256, 0, stream>>>(counts, bbases, off, cursor);
    scatter_kernel<<<(N_EDGES + 255) / 256, 256, 0, stream>>>(esrc, edst, ew, cursor, epack);

    bfrag_kernel<<<(KTILES * 4 * 64 + 255) / 256, 256, 0, stream>>>(m1w, bfrag);
    encoder_kernel<<<(N_NODES + 15) / 16, 256, 0, stream>>>(x, bfrag, m1b, x0H, zH);

    const float dt = 1.0f / STEPS;
    int sgrid = (N_NODES + 31) / 32;
    for (int step = 0; step < STEPS; ++step) {
        stage_kernel<0><<<sgrid, 256, 0, stream>>>(off, epack, zH,   zH, x0H, alpha, accH, ztAH, 0.5f * dt);
        stage_kernel<1><<<sgrid, 256, 0, stream>>>(off, epack, ztAH, zH, x0H, alpha, accH, ztBH, 0.5f * dt);
        stage_kernel<2><<<sgrid, 256, 0, stream>>>(off, epack, ztBH, zH, x0H, alpha, accH, ztAH, dt);
        stage_kernel<3><<<sgrid, 256, 0, stream>>>(off, epack, ztAH, zH, x0H, alpha, accH, zH,   dt / 6.0f);
    }

    decoder_kernel<<<(N_NODES + 3) / 4, 256, 0, stream>>>(zH, m2w, m2b, out);
}